// Round 19
// baseline (305.328 us; speedup 1.0000x reference)
//
#include <hip/hip_runtime.h>
#include <hip/hip_fp16.h>

#define NN 50000
#define EE 800000
#define NCHUNK 784          // 784 chunks of 64 nodes = 50176 >= NN

typedef unsigned int u32;
typedef unsigned short u16;
typedef _Float16 f16x8 __attribute__((ext_vector_type(8)));
typedef float f32x4 __attribute__((ext_vector_type(4)));

// ---------- helpers ----------
__device__ __forceinline__ float bf_lo(u32 u){ return __uint_as_float(u << 16); }
__device__ __forceinline__ float bf_hi(u32 u){ return __uint_as_float(u & 0xffff0000u); }
__device__ __forceinline__ u16 f2bf(float f){
  u32 x = __float_as_uint(f);
  x += 0x7fffu + ((x >> 16) & 1u);       // RNE
  return (u16)(x >> 16);
}
__device__ __forceinline__ float gelu_exact(float x){
  return x * 0.5f * (1.0f + erff(x * 0.70710678118654752f));
}
__device__ __forceinline__ float rcp_fast(float x){ return __builtin_amdgcn_rcpf(x); }
__device__ __forceinline__ float gelu_fast(float x){
  float x2 = x * x;
  float y  = x * fmaf(x2, 0.0356774081f, 0.7978845608f);
  float e  = __expf(y + y);
  return x - x * rcp_fast(e + 1.0f);
}
__device__ __forceinline__ float tanh_fast(float x){
  float e = __expf(x + x);
  return 1.0f - 2.0f * rcp_fast(e + 1.0f);
}
__device__ __forceinline__ int atomic_inc_i32(int* p){
  return __hip_atomic_fetch_add(p, 1, __ATOMIC_RELAXED, __HIP_MEMORY_SCOPE_AGENT);
}
__device__ __forceinline__ __half2 as_h2(u32 u){ return __builtin_bit_cast(__half2, u); }
__device__ __forceinline__ u32 pack2f(float a, float b){
  __half2 h = __floats2half2_rn(a, b);
  return __builtin_bit_cast(u32, h);
}
__device__ __forceinline__ float h2_lo(__half2 h){ return __half2float(__low2half(h)); }
__device__ __forceinline__ float h2_hi(__half2 h){ return __half2float(__high2half(h)); }

union FragU { uint4 u; f16x8 v; };

// ---------- CSR build ----------
__global__ __launch_bounds__(256) void count_k(const int* __restrict__ ei, int* __restrict__ deg)
{
  int e = blockIdx.x * 256 + threadIdx.x;
  atomic_inc_i32(&deg[ei[EE + e]]);
}

__global__ __launch_bounds__(256) void chunksum_k(const int* __restrict__ deg, int* __restrict__ csum)
{
  const int c = blockIdx.x * 4 + (threadIdx.x >> 6);
  const int lane = threadIdx.x & 63;
  const int idx = c * 64 + lane;
  int v = (idx < NN) ? deg[idx] : 0;
  #pragma unroll
  for (int o = 1; o < 64; o <<= 1) v += __shfl_xor(v, o);
  if (lane == 0) csum[c] = v;
}

__global__ __launch_bounds__(64) void chunkscan_k(const int* __restrict__ csum, int* __restrict__ cbase)
{
  const int lane = threadIdx.x;
  const int CH = 13;
  const int base = lane * CH;
  int s = 0;
  #pragma unroll
  for (int j = 0; j < CH; j++) {
    int c = base + j;
    s += (c < NCHUNK) ? csum[c] : 0;
  }
  int inc = s;
  #pragma unroll
  for (int off = 1; off < 64; off <<= 1) {
    int v = __shfl_up(inc, off);
    if (lane >= off) inc += v;
  }
  int run = inc - s;
  #pragma unroll
  for (int j = 0; j < CH; j++) {
    int c = base + j;
    if (c < NCHUNK) {
      cbase[c] = run;
      run += csum[c];
    }
  }
}

__global__ __launch_bounds__(256) void writeoffs_k(
    const int* __restrict__ deg, const int* __restrict__ cbase,
    int* __restrict__ offs, int* __restrict__ cursor)
{
  const int c = blockIdx.x * 4 + (threadIdx.x >> 6);
  const int lane = threadIdx.x & 63;
  const int idx = c * 64 + lane;
  int d = (idx < NN) ? deg[idx] : 0;
  int inc = d;
  #pragma unroll
  for (int off = 1; off < 64; off <<= 1) {
    int v = __shfl_up(inc, off);
    if (lane >= off) inc += v;
  }
  int off_ = cbase[c] + inc - d;
  if (idx < NN) {
    offs[idx] = off_;
    cursor[idx] = off_;
  }
}

// CSR-ordered arrays: psrc (src node), pe (edge id), dstOf (dst node)
__global__ __launch_bounds__(256) void scatter_pairs_k(
    const int* __restrict__ ei, int* __restrict__ cursor,
    int* __restrict__ psrc, int* __restrict__ pe, int* __restrict__ dstOf)
{
  int e = blockIdx.x * 256 + threadIdx.x;
  int src = ei[e];
  int dst = ei[EE + e];
  int pos = atomic_inc_i32(&cursor[dst]);
  psrc[pos]  = src;
  pe[pos]    = e;
  dstOf[pos] = dst;
}

// ---------- kernel 0: edge-type MLP, edge-order streaming -> mtab (f16 x 8) ----------
__global__ __launch_bounds__(256) void edgemlp_k(
    const float* __restrict__ edge_attr,
    const float* __restrict__ We0a, const float* __restrict__ be0a,
    const float* __restrict__ We0b, const float* __restrict__ be0b,
    const float* __restrict__ We1a, const float* __restrict__ be1a,
    const float* __restrict__ We1b, const float* __restrict__ be1b,
    uint4* __restrict__ mtab)
{
  __shared__ u32   sWeah[2 * 264];
  __shared__ u32   sWebTh[2 * 136];
  __shared__ float sbea[64];
  __shared__ float sbeb[16];

  const int t = threadIdx.x;
  for (int idx = t; idx < 512; idx += 256) {
    int e2 = idx >> 8, rem = idx & 255, j = rem >> 3, q = rem & 7;
    const float* W = e2 ? We1a : We0a;
    sWeah[e2 * 264 + rem] = pack2f(W[j * 16 + 2 * q], W[j * 16 + 2 * q + 1]);
  }
  {
    int e2 = t >> 7, rem = t & 127, j = rem >> 2, q = rem & 3;
    const float* W = e2 ? We1b : We0b;
    sWebTh[e2 * 136 + rem] = pack2f(W[(2 * q) * 32 + j], W[(2 * q + 1) * 32 + j]);
  }
  if (t < 64) sbea[t] = (t < 32) ? be0a[t] : be1a[t - 32];
  if (t < 16) sbeb[t] = (t < 8) ? be0b[t] : be1b[t - 8];
  __syncthreads();

  const int e = blockIdx.x * 256 + t;

  __half2 ef2[8]; float a16, a17;
  {
    const float2* p2 = (const float2*)(edge_attr + (size_t)e * 18);
    float2 p[9];
    #pragma unroll
    for (int i = 0; i < 9; i++) p[i] = p2[i];
    #pragma unroll
    for (int i = 0; i < 8; i++) ef2[i] = __floats2half2_rn(p[i].x, p[i].y);
    a16 = p[8].x; a17 = p[8].y;
  }
  const int sel = (a17 > a16) ? 1 : 0;
  const u32* Wah = sWeah + sel * 264;
  const u32* Wbh = sWebTh + sel * 136;
  const float* ba = sbea + sel * 32;
  const float* bb = sbeb + sel * 8;

  __half2 m2[4];
  #pragma unroll
  for (int q = 0; q < 4; q++) m2[q] = __floats2half2_rn(bb[2 * q], bb[2 * q + 1]);
  for (int j = 0; j < 32; j++) {
    __half2 a = __floats2half2_rn(0.f, 0.f);
    #pragma unroll
    for (int q = 0; q < 8; q++) a = __hfma2(as_h2(Wah[j * 8 + q]), ef2[q], a);
    float hs = h2_lo(a) + h2_hi(a) + ba[j];
    hs = fmaxf(hs, 0.f);
    __half2 hs2 = __float2half2_rn(hs);
    #pragma unroll
    for (int q = 0; q < 4; q++) m2[q] = __hfma2(as_h2(Wbh[j * 4 + q]), hs2, m2[q]);
  }
  uint4 st;
  st.x = __builtin_bit_cast(u32, m2[0]);
  st.y = __builtin_bit_cast(u32, m2[1]);
  st.z = __builtin_bit_cast(u32, m2[2]);
  st.w = __builtin_bit_cast(u32, m2[3]);
  mtab[e] = st;
}

// ---------- kernel 1: LN + seq-normalize + MFMA QKV ----------
__global__ __launch_bounds__(512) void node_pre(
    const float* __restrict__ x, const float* __restrict__ seq,
    const float* __restrict__ ln_g, const float* __restrict__ ln_b,
    const float* __restrict__ Wq, const float* __restrict__ bq,
    const float* __restrict__ Wk, const float* __restrict__ bk,
    const float* __restrict__ Wv, const float* __restrict__ bv,
    __half* __restrict__ qb, __half* __restrict__ kb,
    u16* __restrict__ vb, __half* __restrict__ snb)
{
  __shared__ __align__(16) u16 h16[64][136];
  const int t = threadIdx.x;
  const int nbase = blockIdx.x * 64;

  {
    const int row = t >> 3, sub = t & 7;
    const int n = nbase + row;
    if (n < NN) {
      const float* xp = x + (size_t)n * 128 + sub * 16;
      float vals[16];
      float s = 0.f, ss = 0.f;
      #pragma unroll
      for (int j = 0; j < 16; j += 4) {
        float4 v4 = *(const float4*)(xp + j);
        vals[j] = v4.x; vals[j+1] = v4.y; vals[j+2] = v4.z; vals[j+3] = v4.w;
        s += v4.x + v4.y + v4.z + v4.w;
        ss += v4.x*v4.x + v4.y*v4.y + v4.z*v4.z + v4.w*v4.w;
      }
      #pragma unroll
      for (int o = 1; o < 8; o <<= 1) { s += __shfl_xor(s, o); ss += __shfl_xor(ss, o); }
      float mu = s * (1.f / 128.f);
      float var = ss * (1.f / 128.f) - mu * mu;
      float rs = rsqrtf(var + 1e-5f);
      #pragma unroll
      for (int j = 0; j < 16; j += 2) {
        int c = sub * 16 + j;
        float v0 = (vals[j]   - mu) * rs * ln_g[c]   + ln_b[c];
        float v1 = (vals[j+1] - mu) * rs * ln_g[c+1] + ln_b[c+1];
        *(u32*)&h16[row][c] = pack2f(v0, v1);
      }
      const float* sp = seq + (size_t)n * 64 + sub * 8;
      float4 a = *(const float4*)(sp);
      float4 b4 = *(const float4*)(sp + 4);
      float q2 = a.x*a.x + a.y*a.y + a.z*a.z + a.w*a.w
               + b4.x*b4.x + b4.y*b4.y + b4.z*b4.z + b4.w*b4.w;
      #pragma unroll
      for (int o = 1; o < 8; o <<= 1) q2 += __shfl_xor(q2, o);
      float inv = 1.0f / fmaxf(sqrtf(q2), 1e-12f);
      __half* op = snb + (size_t)n * 64 + sub * 8;
      op[0]=__float2half(a.x*inv);  op[1]=__float2half(a.y*inv);
      op[2]=__float2half(a.z*inv);  op[3]=__float2half(a.w*inv);
      op[4]=__float2half(b4.x*inv); op[5]=__float2half(b4.y*inv);
      op[6]=__float2half(b4.z*inv); op[7]=__float2half(b4.w*inv);
    }
  }

  const int lane = t & 63, wid = t >> 6;
  const int lr = lane & 15;
  const int lk = lane >> 4;
  const int tile0 = wid * 3;

  FragU Bf[3][4];
  float bias[3];
  #pragma unroll
  for (int ti = 0; ti < 3; ti++) {
    int tile = tile0 + ti;
    int mat = tile >> 3;
    int colm = (tile & 7) * 16 + lr;
    const float* W = (mat == 0) ? Wq : (mat == 1) ? Wk : Wv;
    const float* B = (mat == 0) ? bq : (mat == 1) ? bk : bv;
    bias[ti] = B[colm];
    const float* wrow = W + (size_t)colm * 128;
    #pragma unroll
    for (int ks = 0; ks < 4; ks++) {
      const float* wp = wrow + ks * 32 + lk * 8;
      float4 wa = *(const float4*)(wp);
      float4 wb = *(const float4*)(wp + 4);
      Bf[ti][ks].u.x = pack2f(wa.x, wa.y);
      Bf[ti][ks].u.y = pack2f(wa.z, wa.w);
      Bf[ti][ks].u.z = pack2f(wb.x, wb.y);
      Bf[ti][ks].u.w = pack2f(wb.z, wb.w);
    }
  }
  __syncthreads();

  #pragma unroll
  for (int mt = 0; mt < 4; mt++) {
    FragU A[4];
    #pragma unroll
    for (int ks = 0; ks < 4; ks++)
      A[ks].u = *(const uint4*)&h16[mt * 16 + lr][ks * 32 + lk * 8];
    #pragma unroll
    for (int ti = 0; ti < 3; ti++) {
      f32x4 acc = { bias[ti], bias[ti], bias[ti], bias[ti] };
      #pragma unroll
      for (int ks = 0; ks < 4; ks++)
        acc = __builtin_amdgcn_mfma_f32_16x16x32_f16(A[ks].v, Bf[ti][ks].v, acc, 0, 0, 0);
      int tile = tile0 + ti;
      int mat = tile >> 3;
      int colm = (tile & 7) * 16 + lr;
      __half* Oh = (mat == 0) ? qb : kb;
      #pragma unroll
      for (int r = 0; r < 4; r++) {
        int node = nbase + mt * 16 + lk * 4 + r;
        if (node < NN) {
          float val = acc[r];
          if (mat == 2) vb[(size_t)node * 128 + colm] = f2bf(val);
          else          Oh[(size_t)node * 128 + colm] = __float2half(val);
        }
      }
    }
  }
}

// ---------- kernel 2: FUSED, CSR-SLOT-ORDERED seq-MLP (MFMA) + mtab + QK + exp ----------
__global__ __launch_bounds__(256, 5) void edge_fused(
    const uint4* __restrict__ mtab,
    const __half* __restrict__ qb, const __half* __restrict__ kb,
    const __half* __restrict__ snb,
    const int* __restrict__ psrc, const int* __restrict__ pe,
    const int* __restrict__ dstOf,
    const float* __restrict__ Ws1, const float* __restrict__ bs1,
    const float* __restrict__ Ws2, const float* __restrict__ bs2,
    uint4* __restrict__ exw)
{
  __shared__ __align__(16) u16 h1lds[4][16][72];    // half-width h1 (+8 pad) / sb redistribution
  __shared__ __align__(16) uint4 sWs1F[1024];       // Ws1 frags (16 KB)
  __shared__ __align__(16) uint4 sWs2F[128];        // Ws2 frags (2 KB)

  const int t = threadIdx.x;
  const int lane = t & 63, wid = t >> 6;
  const int lr = lane & 15;
  const int lk = lane >> 4;
  const int ibase = blockIdx.x * 256 + wid * 64;    // CSR slot base for this wave

  // --- stage seq-MLP weight FRAGMENTS into LDS ---
  for (int fid = t; fid < 1024; fid += 256) {
    int lf = fid & 63, tk = (fid >> 6) & 1, jt = fid >> 7;
    int lrf = lf & 15, lkf = lf >> 4;
    const float* wp = Ws1 + (size_t)(jt * 16 + lrf) * 64 + tk * 32 + lkf * 8;
    float4 wa = *(const float4*)(wp);
    float4 wb = *(const float4*)(wp + 4);
    uint4 fr;
    fr.x = pack2f(wa.x, wa.y); fr.y = pack2f(wa.z, wa.w);
    fr.z = pack2f(wb.x, wb.y); fr.w = pack2f(wb.z, wb.w);
    sWs1F[fid] = fr;
  }
  if (t < 128) {
    int lrf = t & 7, lkf = (t >> 3) & 3, tk = t >> 5;
    const float* wp = Ws2 + (size_t)lrf * 128 + tk * 32 + lkf * 8;
    float4 wa = *(const float4*)(wp);
    float4 wb = *(const float4*)(wp + 4);
    uint4 fr;
    fr.x = pack2f(wa.x, wa.y); fr.y = pack2f(wa.z, wa.w);
    fr.z = pack2f(wb.x, wb.y); fr.w = pack2f(wb.z, wb.w);
    sWs2F[t] = fr;
  }

  float b1v[8];
  #pragma unroll
  for (int jt = 0; jt < 8; jt++) b1v[jt] = bs1[jt * 16 + lr];
  const float b2v = (lr < 8) ? bs2[lr] : 0.f;

  const int srcR = psrc[ibase + lane];     // coalesced
  const int dstR = dstOf[ibase + lane];    // coalesced, ~segment-constant
  const int eR   = pe[ibase + lane];       // coalesced read, random values
  const char* snbB = (const char*)snb;

  __syncthreads();

  // --- phase A: seq-MLP (MFMA), 4 groups of 16 slots; split GEMM2 ---
  float sbreg[16];
  #pragma unroll
  for (int g = 0; g < 4; g++) {
    const int d_e = __shfl(dstR, g * 16 + lr);
    const int s_e = __shfl(srcR, g * 16 + lr);
    FragU A0, A1;
    {
      uint4 ua = *(const uint4*)(snbB + (size_t)d_e * 128 + 0 * 64 + lk * 16);
      uint4 ub = *(const uint4*)(snbB + (size_t)s_e * 128 + 0 * 64 + lk * 16);
      A0.u.x = __builtin_bit_cast(u32, __hsub2(as_h2(ua.x), as_h2(ub.x)));
      A0.u.y = __builtin_bit_cast(u32, __hsub2(as_h2(ua.y), as_h2(ub.y)));
      A0.u.z = __builtin_bit_cast(u32, __hsub2(as_h2(ua.z), as_h2(ub.z)));
      A0.u.w = __builtin_bit_cast(u32, __hsub2(as_h2(ua.w), as_h2(ub.w)));
      uint4 uc = *(const uint4*)(snbB + (size_t)d_e * 128 + 1 * 64 + lk * 16);
      uint4 ud = *(const uint4*)(snbB + (size_t)s_e * 128 + 1 * 64 + lk * 16);
      A1.u.x = __builtin_bit_cast(u32, __hsub2(as_h2(uc.x), as_h2(ud.x)));
      A1.u.y = __builtin_bit_cast(u32, __hsub2(as_h2(uc.y), as_h2(ud.y)));
      A1.u.z = __builtin_bit_cast(u32, __hsub2(as_h2(uc.z), as_h2(ud.z)));
      A1.u.w = __builtin_bit_cast(u32, __hsub2(as_h2(uc.w), as_h2(ud.w)));
    }
    f32x4 acc2 = { b2v, b2v, b2v, b2v };
    #pragma unroll
    for (int jt = 0; jt < 4; jt++) {
      FragU Bf0, Bf1;
      Bf0.u = sWs1F[(jt * 2 + 0) * 64 + lane];
      Bf1.u = sWs1F[(jt * 2 + 1) * 64 + lane];
      f32x4 acc = { b1v[jt], b1v[jt], b1v[jt], b1v[jt] };
      acc = __builtin_amdgcn_mfma_f32_16x16x32_f16(A0.v, Bf0.v, acc, 0, 0, 0);
      acc = __builtin_amdgcn_mfma_f32_16x16x32_f16(A1.v, Bf1.v, acc, 0, 0, 0);
      #pragma unroll
      for (int r = 0; r < 4; r++) {
        float gg = gelu_fast(acc[r]);
        h1lds[wid][lk * 4 + r][jt * 16 + lr] = __builtin_bit_cast(u16, (_Float16)gg);
      }
    }
    #pragma unroll
    for (int tk = 0; tk < 2; tk++) {
      FragU A2, B2f;
      A2.u = *(const uint4*)&h1lds[wid][lr][tk * 32 + lk * 8];
      if (lr < 8) B2f.u = sWs2F[tk * 32 + lk * 8 + lr];
      else        B2f.u = make_uint4(0, 0, 0, 0);
      acc2 = __builtin_amdgcn_mfma_f32_16x16x32_f16(A2.v, B2f.v, acc2, 0, 0, 0);
    }
    #pragma unroll
    for (int jt = 4; jt < 8; jt++) {
      FragU Bf0, Bf1;
      Bf0.u = sWs1F[(jt * 2 + 0) * 64 + lane];
      Bf1.u = sWs1F[(jt * 2 + 1) * 64 + lane];
      f32x4 acc = { b1v[jt], b1v[jt], b1v[jt], b1v[jt] };
      acc = __builtin_amdgcn_mfma_f32_16x16x32_f16(A0.v, Bf0.v, acc, 0, 0, 0);
      acc = __builtin_amdgcn_mfma_f32_16x16x32_f16(A1.v, Bf1.v, acc, 0, 0, 0);
      #pragma unroll
      for (int r = 0; r < 4; r++) {
        float gg = gelu_fast(acc[r]);
        h1lds[wid][lk * 4 + r][(jt - 4) * 16 + lr] = __builtin_bit_cast(u16, (_Float16)gg);
      }
    }
    #pragma unroll
    for (int tk = 2; tk < 4; tk++) {
      FragU A2, B2f;
      A2.u = *(const uint4*)&h1lds[wid][lr][(tk - 2) * 32 + lk * 8];
      if (lr < 8) B2f.u = sWs2F[tk * 32 + lk * 8 + lr];
      else        B2f.u = make_uint4(0, 0, 0, 0);
      acc2 = __builtin_amdgcn_mfma_f32_16x16x32_f16(A2.v, B2f.v, acc2, 0, 0, 0);
    }
    #pragma unroll
    for (int r = 0; r < 4; r++) sbreg[g * 4 + r] = acc2[r];
  }

  // --- sb redistribution through h1lds (wave-private reuse) ---
  u16* sbuf = &h1lds[wid][0][0];
  if (lr < 8) {
    #pragma unroll
    for (int g = 0; g < 4; g++)
      #pragma unroll
      for (int r = 0; r < 4; r++)
        sbuf[(g * 16 + lk * 4 + r) * 8 + lr] =
            __builtin_bit_cast(u16, (_Float16)sbreg[g * 4 + r]);
  }

  // --- phase B: thread-per-slot ---
  const int src = srcR;
  const int dst = dstR;

  float m[8];
  {
    uint4 mm = mtab[eR];        // 16 B scattered, L3-resident table
    u32 wv[4] = {mm.x, mm.y, mm.z, mm.w};
    #pragma unroll
    for (int q = 0; q < 4; q++) {
      m[2*q]   = h2_lo(as_h2(wv[q]));
      m[2*q+1] = h2_hi(as_h2(wv[q]));
    }
  }

  float tv[8];
  {
    uint4 sb4 = ((const uint4*)sbuf)[lane];
    u32 wv[4] = {sb4.x, sb4.y, sb4.z, sb4.w};
    #pragma unroll
    for (int q = 0; q < 4; q++) {
      tv[2*q]   = tanh_fast(h2_lo(as_h2(wv[q])));
      tv[2*q+1] = tanh_fast(h2_hi(as_h2(wv[q])));
    }
  }

  {
    const uint4* qp4 = (const uint4*)(qb + (size_t)dst * 128);
    const uint4* kp4 = (const uint4*)(kb + (size_t)src * 128);
    float ex[8];
    #pragma unroll
    for (int h = 0; h < 8; h++) {
      uint4 qa = qp4[2*h], qc = qp4[2*h+1];
      uint4 ka = kp4[2*h], kc = kp4[2*h+1];
      __half2 d2 = __floats2half2_rn(0.f, 0.f);
      d2 = __hfma2(as_h2(qa.x), as_h2(ka.x), d2);
      d2 = __hfma2(as_h2(qa.y), as_h2(ka.y), d2);
      d2 = __hfma2(as_h2(qa.z), as_h2(ka.z), d2);
      d2 = __hfma2(as_h2(qa.w), as_h2(ka.w), d2);
      d2 = __hfma2(as_h2(qc.x), as_h2(kc.x), d2);
      d2 = __hfma2(as_h2(qc.y), as_h2(kc.y), d2);
      d2 = __hfma2(as_h2(qc.z), as_h2(kc.z), d2);
      d2 = __hfma2(as_h2(qc.w), as_h2(kc.w), d2);
      float dot = h2_lo(d2) + h2_hi(d2);
      float logit = dot * 0.25f + m[h] + 0.1f * tv[h];
      ex[h] = __expf(logit);
    }
    uint4 st;
    st.x = (u32)f2bf(ex[0]) | ((u32)f2bf(ex[1]) << 16);
    st.y = (u32)f2bf(ex[2]) | ((u32)f2bf(ex[3]) << 16);
    st.z = (u32)f2bf(ex[4]) | ((u32)f2bf(ex[5]) << 16);
    st.w = (u32)f2bf(ex[6]) | ((u32)f2bf(ex[7]) << 16);
    exw[ibase + lane] = st;    // coalesced, CSR-ordered
  }
}

// ---------- kernel 3: wave-per-node CSR aggregate (8-deep) + gelu + residual ----------
__global__ __launch_bounds__(256) void aggregate_k(
    const int* __restrict__ offs, const int* __restrict__ deg,
    const int* __restrict__ psrc, const u32* __restrict__ exw,
    const u32* __restrict__ vb32, const float* __restrict__ x,
    float* __restrict__ out)
{
  const int n = (blockIdx.x * 256 + threadIdx.x) >> 6;   // wave per node
  const int lane = threadIdx.x & 63;
  if (n >= NN) return;
  const int s = offs[n];
  const int end = s + deg[n];
  const int word  = lane >> 4;
  const int shift = ((lane >> 3) & 1) << 4;

  float s0 = 0.f, s1 = 0.f, dn = 0.f;
  int i = s;
  for (; i + 8 <= end; i += 8) {
    int  pp[8]; u32 kk[8]; u32 vv[8];
    #pragma unroll
    for (int q = 0; q < 8; q++) pp[q] = psrc[i + q];
    #pragma unroll
    for (int q = 0; q < 8; q++) kk[q] = exw[(size_t)(i + q) * 4 + word];
    #pragma unroll
    for (int q = 0; q < 8; q++) vv[q] = vb32[(size_t)pp[q] * 64 + lane];
    #pragma unroll
    for (int q = 0; q < 8; q++) {
      float ex = __uint_as_float(((kk[q] >> shift) & 0xffffu) << 16);
      s0 = fmaf(bf_lo(vv[q]), ex, s0);
      s1 = fmaf(bf_hi(vv[q]), ex, s1);
      dn += ex;
    }
  }
  for (; i < end; i++) {
    int sp = psrc[i];
    u32 pkv = exw[(size_t)i * 4 + word];
    float ex = __uint_as_float(((pkv >> shift) & 0xffffu) << 16);
    u32 vv = vb32[(size_t)sp * 64 + lane];
    s0 = fmaf(bf_lo(vv), ex, s0);
    s1 = fmaf(bf_hi(vv), ex, s1);
    dn += ex;
  }
  float inv = 1.0f / (dn + 1e-12f);
  float2 xx = *(const float2*)(x + (size_t)n * 128 + lane * 2);
  float2 o;
  o.x = gelu_exact(s0 * inv) + xx.x;
  o.y = gelu_exact(s1 * inv) + xx.y;
  *(float2*)(out + (size_t)n * 128 + lane * 2) = o;
}

extern "C" void kernel_launch(void* const* d_in, const int* in_sizes, int n_in,
                              void* d_out, int out_size, void* d_ws, size_t ws_size,
                              hipStream_t stream)
{
  const float* x    = (const float*)d_in[0];
  const int*   ei   = (const int*)d_in[1];
  const float* ea   = (const float*)d_in[2];
  const float* seq  = (const float*)d_in[3];
  const float* ln_g = (const float*)d_in[4];
  const float* ln_b = (const float*)d_in[5];
  const float* Wq   = (const float*)d_in[6];
  const float* bq   = (const float*)d_in[7];
  const float* Wk   = (const float*)d_in[8];
  const float* bk   = (const float*)d_in[9];
  const float* Wv   = (const float*)d_in[10];
  const float* bv   = (const float*)d_in[11];
  const float* We0a = (const float*)d_in[12];
  const float* be0a = (const float*)d_in[13];
  const float* We0b = (const float*)d_in[14];
  const float* be0b = (const float*)d_in[15];
  const float* We1a = (const float*)d_in[16];
  const float* be1a = (const float*)d_in[17];
  const float* We1b = (const float*)d_in[18];
  const float* be1b = (const float*)d_in[19];
  const float* Ws1  = (const float*)d_in[20];
  const float* bs1  = (const float*)d_in[21];
  const float* Ws2  = (const float*)d_in[22];
  const float* bs2  = (const float*)d_in[23];
  float* out = (float*)d_out;

  // workspace layout (~81 MB)
  char* w = (char*)d_ws;
  __half* qb   = (__half*)w;                       w += (size_t)NN * 128 * 2;
  __half* kb   = (__half*)w;                       w += (size_t)NN * 128 * 2;
  u16*    vb   = (u16*)w;                          w += (size_t)NN * 128 * 2;
  __half* snb  = (__half*)w;                       w += (size_t)NN * 64 * 2;
  uint4*  exw  = (uint4*)w;                        w += (size_t)EE * 16;
  uint4*  mtab = (uint4*)w;                        w += (size_t)EE * 16;
  int*    psrc = (int*)w;                          w += (size_t)EE * 4;
  int*    pe   = (int*)w;                          w += (size_t)EE * 4;
  int*    dstOf= (int*)w;                          w += (size_t)EE * 4;
  int*    deg  = (int*)w;                          w += (size_t)NN * 4;
  int*    offs = (int*)w;                          w += (size_t)NN * 4;
  int*    cursor = (int*)w;                        w += (size_t)NN * 4;
  int*    csum = (int*)w;                          w += (size_t)NCHUNK * 4;
  int*    cbase = (int*)w;                         w += (size_t)NCHUNK * 4;

  (void)hipMemsetAsync(deg, 0, (size_t)NN * 4, stream);

  count_k<<<EE / 256, 256, 0, stream>>>(ei, deg);
  chunksum_k<<<NCHUNK / 4, 256, 0, stream>>>(deg, csum);
  chunkscan_k<<<1, 64, 0, stream>>>(csum, cbase);
  writeoffs_k<<<NCHUNK / 4, 256, 0, stream>>>(deg, cbase, offs, cursor);
  scatter_pairs_k<<<EE / 256, 256, 0, stream>>>(ei, cursor, psrc, pe, dstOf);

  edgemlp_k<<<EE / 256, 256, 0, stream>>>(
      ea, We0a, be0a, We0b, be0b, We1a, be1a, We1b, be1b, mtab);

  node_pre<<<(NN + 63) / 64, 512, 0, stream>>>(
      x, seq, ln_g, ln_b, Wq, bq, Wk, bk, Wv, bv, qb, kb, vb, snb);

  edge_fused<<<EE / 256, 256, 0, stream>>>(
      mtab, qb, kb, snb, psrc, pe, dstOf,
      Ws1, bs1, Ws2, bs2, exw);

  aggregate_k<<<(NN * 64) / 256, 256, 0, stream>>>(
      offs, deg, psrc, (const u32*)exw, (const u32*)vb, x, out);
}

// Round 20
// 292.857 us; speedup vs baseline: 1.0426x; 1.0426x over previous
//
#include <hip/hip_runtime.h>
#include <hip/hip_fp16.h>

#define NN 50000
#define EE 800000
#define NCHUNK 784          // 784 chunks of 64 nodes = 50176 >= NN

typedef unsigned int u32;
typedef unsigned short u16;
typedef _Float16 f16x8 __attribute__((ext_vector_type(8)));
typedef float f32x4 __attribute__((ext_vector_type(4)));

// ---------- helpers ----------
__device__ __forceinline__ float bf_lo(u32 u){ return __uint_as_float(u << 16); }
__device__ __forceinline__ float bf_hi(u32 u){ return __uint_as_float(u & 0xffff0000u); }
__device__ __forceinline__ u16 f2bf(float f){
  u32 x = __float_as_uint(f);
  x += 0x7fffu + ((x >> 16) & 1u);       // RNE
  return (u16)(x >> 16);
}
__device__ __forceinline__ float gelu_exact(float x){
  return x * 0.5f * (1.0f + erff(x * 0.70710678118654752f));
}
__device__ __forceinline__ float rcp_fast(float x){ return __builtin_amdgcn_rcpf(x); }
__device__ __forceinline__ float gelu_fast(float x){
  float x2 = x * x;
  float y  = x * fmaf(x2, 0.0356774081f, 0.7978845608f);
  float e  = __expf(y + y);
  return x - x * rcp_fast(e + 1.0f);
}
__device__ __forceinline__ float tanh_fast(float x){
  float e = __expf(x + x);
  return 1.0f - 2.0f * rcp_fast(e + 1.0f);
}
__device__ __forceinline__ int atomic_inc_i32(int* p){
  return __hip_atomic_fetch_add(p, 1, __ATOMIC_RELAXED, __HIP_MEMORY_SCOPE_AGENT);
}
__device__ __forceinline__ __half2 as_h2(u32 u){ return __builtin_bit_cast(__half2, u); }
__device__ __forceinline__ u32 pack2f(float a, float b){
  __half2 h = __floats2half2_rn(a, b);
  return __builtin_bit_cast(u32, h);
}
__device__ __forceinline__ float h2_lo(__half2 h){ return __half2float(__low2half(h)); }
__device__ __forceinline__ float h2_hi(__half2 h){ return __half2float(__high2half(h)); }

union FragU { uint4 u; f16x8 v; };

// ---------- kernel 0: fused degree count + edge-type MLP (both edge-order) ----------
// The ~700 VALU ops of the MLP hide under the deg atomic + ea load latency.
__global__ __launch_bounds__(256) void count_mlp_k(
    const int* __restrict__ ei, const float* __restrict__ edge_attr,
    const float* __restrict__ We0a, const float* __restrict__ be0a,
    const float* __restrict__ We0b, const float* __restrict__ be0b,
    const float* __restrict__ We1a, const float* __restrict__ be1a,
    const float* __restrict__ We1b, const float* __restrict__ be1b,
    int* __restrict__ deg, uint4* __restrict__ mtab)
{
  __shared__ u32   sWeah[2 * 264];
  __shared__ u32   sWebTh[2 * 136];
  __shared__ float sbea[64];
  __shared__ float sbeb[16];

  const int t = threadIdx.x;
  for (int idx = t; idx < 512; idx += 256) {
    int e2 = idx >> 8, rem = idx & 255, j = rem >> 3, q = rem & 7;
    const float* W = e2 ? We1a : We0a;
    sWeah[e2 * 264 + rem] = pack2f(W[j * 16 + 2 * q], W[j * 16 + 2 * q + 1]);
  }
  {
    int e2 = t >> 7, rem = t & 127, j = rem >> 2, q = rem & 3;
    const float* W = e2 ? We1b : We0b;
    sWebTh[e2 * 136 + rem] = pack2f(W[(2 * q) * 32 + j], W[(2 * q + 1) * 32 + j]);
  }
  if (t < 64) sbea[t] = (t < 32) ? be0a[t] : be1a[t - 32];
  if (t < 16) sbeb[t] = (t < 8) ? be0b[t] : be1b[t - 8];
  __syncthreads();

  const int e = blockIdx.x * 256 + t;

  // degree count (atomic, latency hidden by MLP below)
  atomic_inc_i32(&deg[ei[EE + e]]);

  __half2 ef2[8]; float a16, a17;
  {
    const float2* p2 = (const float2*)(edge_attr + (size_t)e * 18);
    float2 p[9];
    #pragma unroll
    for (int i = 0; i < 9; i++) p[i] = p2[i];
    #pragma unroll
    for (int i = 0; i < 8; i++) ef2[i] = __floats2half2_rn(p[i].x, p[i].y);
    a16 = p[8].x; a17 = p[8].y;
  }
  const int sel = (a17 > a16) ? 1 : 0;
  const u32* Wah = sWeah + sel * 264;
  const u32* Wbh = sWebTh + sel * 136;
  const float* ba = sbea + sel * 32;
  const float* bb = sbeb + sel * 8;

  __half2 m2[4];
  #pragma unroll
  for (int q = 0; q < 4; q++) m2[q] = __floats2half2_rn(bb[2 * q], bb[2 * q + 1]);
  for (int j = 0; j < 32; j++) {
    __half2 a = __floats2half2_rn(0.f, 0.f);
    #pragma unroll
    for (int q = 0; q < 8; q++) a = __hfma2(as_h2(Wah[j * 8 + q]), ef2[q], a);
    float hs = h2_lo(a) + h2_hi(a) + ba[j];
    hs = fmaxf(hs, 0.f);
    __half2 hs2 = __float2half2_rn(hs);
    #pragma unroll
    for (int q = 0; q < 4; q++) m2[q] = __hfma2(as_h2(Wbh[j * 4 + q]), hs2, m2[q]);
  }
  uint4 st;
  st.x = __builtin_bit_cast(u32, m2[0]);
  st.y = __builtin_bit_cast(u32, m2[1]);
  st.z = __builtin_bit_cast(u32, m2[2]);
  st.w = __builtin_bit_cast(u32, m2[3]);
  mtab[e] = st;
}

// ---------- CSR build ----------
__global__ __launch_bounds__(256) void chunksum_k(const int* __restrict__ deg, int* __restrict__ csum)
{
  const int c = blockIdx.x * 4 + (threadIdx.x >> 6);
  const int lane = threadIdx.x & 63;
  const int idx = c * 64 + lane;
  int v = (idx < NN) ? deg[idx] : 0;
  #pragma unroll
  for (int o = 1; o < 64; o <<= 1) v += __shfl_xor(v, o);
  if (lane == 0) csum[c] = v;
}

__global__ __launch_bounds__(64) void chunkscan_k(const int* __restrict__ csum, int* __restrict__ cbase)
{
  const int lane = threadIdx.x;
  const int CH = 13;
  const int base = lane * CH;
  int s = 0;
  #pragma unroll
  for (int j = 0; j < CH; j++) {
    int c = base + j;
    s += (c < NCHUNK) ? csum[c] : 0;
  }
  int inc = s;
  #pragma unroll
  for (int off = 1; off < 64; off <<= 1) {
    int v = __shfl_up(inc, off);
    if (lane >= off) inc += v;
  }
  int run = inc - s;
  #pragma unroll
  for (int j = 0; j < CH; j++) {
    int c = base + j;
    if (c < NCHUNK) {
      cbase[c] = run;
      run += csum[c];
    }
  }
}

__global__ __launch_bounds__(256) void writeoffs_k(
    const int* __restrict__ deg, const int* __restrict__ cbase,
    int* __restrict__ offs, int* __restrict__ cursor)
{
  const int c = blockIdx.x * 4 + (threadIdx.x >> 6);
  const int lane = threadIdx.x & 63;
  const int idx = c * 64 + lane;
  int d = (idx < NN) ? deg[idx] : 0;
  int inc = d;
  #pragma unroll
  for (int off = 1; off < 64; off <<= 1) {
    int v = __shfl_up(inc, off);
    if (lane >= off) inc += v;
  }
  int off_ = cbase[c] + inc - d;
  if (idx < NN) {
    offs[idx] = off_;
    cursor[idx] = off_;
  }
}

// CSR-ordered arrays: psrc (src node), pe (edge id), dstOf (dst node)
__global__ __launch_bounds__(256) void scatter_pairs_k(
    const int* __restrict__ ei, int* __restrict__ cursor,
    int* __restrict__ psrc, int* __restrict__ pe, int* __restrict__ dstOf)
{
  int e = blockIdx.x * 256 + threadIdx.x;
  int src = ei[e];
  int dst = ei[EE + e];
  int pos = atomic_inc_i32(&cursor[dst]);
  psrc[pos]  = src;
  pe[pos]    = e;
  dstOf[pos] = dst;
}

// ---------- kernel 1: LN + seq-normalize + MFMA QKV ----------
__global__ __launch_bounds__(512) void node_pre(
    const float* __restrict__ x, const float* __restrict__ seq,
    const float* __restrict__ ln_g, const float* __restrict__ ln_b,
    const float* __restrict__ Wq, const float* __restrict__ bq,
    const float* __restrict__ Wk, const float* __restrict__ bk,
    const float* __restrict__ Wv, const float* __restrict__ bv,
    __half* __restrict__ qb, __half* __restrict__ kb,
    u16* __restrict__ vb, __half* __restrict__ snb)
{
  __shared__ __align__(16) u16 h16[64][136];
  const int t = threadIdx.x;
  const int nbase = blockIdx.x * 64;

  {
    const int row = t >> 3, sub = t & 7;
    const int n = nbase + row;
    if (n < NN) {
      const float* xp = x + (size_t)n * 128 + sub * 16;
      float vals[16];
      float s = 0.f, ss = 0.f;
      #pragma unroll
      for (int j = 0; j < 16; j += 4) {
        float4 v4 = *(const float4*)(xp + j);
        vals[j] = v4.x; vals[j+1] = v4.y; vals[j+2] = v4.z; vals[j+3] = v4.w;
        s += v4.x + v4.y + v4.z + v4.w;
        ss += v4.x*v4.x + v4.y*v4.y + v4.z*v4.z + v4.w*v4.w;
      }
      #pragma unroll
      for (int o = 1; o < 8; o <<= 1) { s += __shfl_xor(s, o); ss += __shfl_xor(ss, o); }
      float mu = s * (1.f / 128.f);
      float var = ss * (1.f / 128.f) - mu * mu;
      float rs = rsqrtf(var + 1e-5f);
      #pragma unroll
      for (int j = 0; j < 16; j += 2) {
        int c = sub * 16 + j;
        float v0 = (vals[j]   - mu) * rs * ln_g[c]   + ln_b[c];
        float v1 = (vals[j+1] - mu) * rs * ln_g[c+1] + ln_b[c+1];
        *(u32*)&h16[row][c] = pack2f(v0, v1);
      }
      const float* sp = seq + (size_t)n * 64 + sub * 8;
      float4 a = *(const float4*)(sp);
      float4 b4 = *(const float4*)(sp + 4);
      float q2 = a.x*a.x + a.y*a.y + a.z*a.z + a.w*a.w
               + b4.x*b4.x + b4.y*b4.y + b4.z*b4.z + b4.w*b4.w;
      #pragma unroll
      for (int o = 1; o < 8; o <<= 1) q2 += __shfl_xor(q2, o);
      float inv = 1.0f / fmaxf(sqrtf(q2), 1e-12f);
      __half* op = snb + (size_t)n * 64 + sub * 8;
      op[0]=__float2half(a.x*inv);  op[1]=__float2half(a.y*inv);
      op[2]=__float2half(a.z*inv);  op[3]=__float2half(a.w*inv);
      op[4]=__float2half(b4.x*inv); op[5]=__float2half(b4.y*inv);
      op[6]=__float2half(b4.z*inv); op[7]=__float2half(b4.w*inv);
    }
  }

  const int lane = t & 63, wid = t >> 6;
  const int lr = lane & 15;
  const int lk = lane >> 4;
  const int tile0 = wid * 3;

  FragU Bf[3][4];
  float bias[3];
  #pragma unroll
  for (int ti = 0; ti < 3; ti++) {
    int tile = tile0 + ti;
    int mat = tile >> 3;
    int colm = (tile & 7) * 16 + lr;
    const float* W = (mat == 0) ? Wq : (mat == 1) ? Wk : Wv;
    const float* B = (mat == 0) ? bq : (mat == 1) ? bk : bv;
    bias[ti] = B[colm];
    const float* wrow = W + (size_t)colm * 128;
    #pragma unroll
    for (int ks = 0; ks < 4; ks++) {
      const float* wp = wrow + ks * 32 + lk * 8;
      float4 wa = *(const float4*)(wp);
      float4 wb = *(const float4*)(wp + 4);
      Bf[ti][ks].u.x = pack2f(wa.x, wa.y);
      Bf[ti][ks].u.y = pack2f(wa.z, wa.w);
      Bf[ti][ks].u.z = pack2f(wb.x, wb.y);
      Bf[ti][ks].u.w = pack2f(wb.z, wb.w);
    }
  }
  __syncthreads();

  #pragma unroll
  for (int mt = 0; mt < 4; mt++) {
    FragU A[4];
    #pragma unroll
    for (int ks = 0; ks < 4; ks++)
      A[ks].u = *(const uint4*)&h16[mt * 16 + lr][ks * 32 + lk * 8];
    #pragma unroll
    for (int ti = 0; ti < 3; ti++) {
      f32x4 acc = { bias[ti], bias[ti], bias[ti], bias[ti] };
      #pragma unroll
      for (int ks = 0; ks < 4; ks++)
        acc = __builtin_amdgcn_mfma_f32_16x16x32_f16(A[ks].v, Bf[ti][ks].v, acc, 0, 0, 0);
      int tile = tile0 + ti;
      int mat = tile >> 3;
      int colm = (tile & 7) * 16 + lr;
      __half* Oh = (mat == 0) ? qb : kb;
      #pragma unroll
      for (int r = 0; r < 4; r++) {
        int node = nbase + mt * 16 + lk * 4 + r;
        if (node < NN) {
          float val = acc[r];
          if (mat == 2) vb[(size_t)node * 128 + colm] = f2bf(val);
          else          Oh[(size_t)node * 128 + colm] = __float2half(val);
        }
      }
    }
  }
}

// ---------- kernel 2: FUSED, CSR-SLOT-ORDERED seq-MLP (MFMA) + mtab + QK + exp ----------
__global__ __launch_bounds__(256, 5) void edge_fused(
    const uint4* __restrict__ mtab,
    const __half* __restrict__ qb, const __half* __restrict__ kb,
    const __half* __restrict__ snb,
    const int* __restrict__ psrc, const int* __restrict__ pe,
    const int* __restrict__ dstOf,
    const float* __restrict__ Ws1, const float* __restrict__ bs1,
    const float* __restrict__ Ws2, const float* __restrict__ bs2,
    uint4* __restrict__ exw)
{
  __shared__ __align__(16) u16 h1lds[4][16][72];    // half-width h1 (+8 pad) / sb redistribution
  __shared__ __align__(16) uint4 sWs1F[1024];       // Ws1 frags (16 KB)
  __shared__ __align__(16) uint4 sWs2F[128];        // Ws2 frags (2 KB)

  const int t = threadIdx.x;
  const int lane = t & 63, wid = t >> 6;
  const int lr = lane & 15;
  const int lk = lane >> 4;
  const int ibase = blockIdx.x * 256 + wid * 64;    // CSR slot base for this wave

  // --- stage seq-MLP weight FRAGMENTS into LDS ---
  for (int fid = t; fid < 1024; fid += 256) {
    int lf = fid & 63, tk = (fid >> 6) & 1, jt = fid >> 7;
    int lrf = lf & 15, lkf = lf >> 4;
    const float* wp = Ws1 + (size_t)(jt * 16 + lrf) * 64 + tk * 32 + lkf * 8;
    float4 wa = *(const float4*)(wp);
    float4 wb = *(const float4*)(wp + 4);
    uint4 fr;
    fr.x = pack2f(wa.x, wa.y); fr.y = pack2f(wa.z, wa.w);
    fr.z = pack2f(wb.x, wb.y); fr.w = pack2f(wb.z, wb.w);
    sWs1F[fid] = fr;
  }
  if (t < 128) {
    int lrf = t & 7, lkf = (t >> 3) & 3, tk = t >> 5;
    const float* wp = Ws2 + (size_t)lrf * 128 + tk * 32 + lkf * 8;
    float4 wa = *(const float4*)(wp);
    float4 wb = *(const float4*)(wp + 4);
    uint4 fr;
    fr.x = pack2f(wa.x, wa.y); fr.y = pack2f(wa.z, wa.w);
    fr.z = pack2f(wb.x, wb.y); fr.w = pack2f(wb.z, wb.w);
    sWs2F[t] = fr;
  }

  float b1v[8];
  #pragma unroll
  for (int jt = 0; jt < 8; jt++) b1v[jt] = bs1[jt * 16 + lr];
  const float b2v = (lr < 8) ? bs2[lr] : 0.f;

  const int srcR = psrc[ibase + lane];     // coalesced
  const int dstR = dstOf[ibase + lane];    // coalesced, ~segment-constant
  const int eR   = pe[ibase + lane];       // coalesced read, random values
  const char* snbB = (const char*)snb;

  __syncthreads();

  // --- phase A: seq-MLP (MFMA), 4 groups of 16 slots; split GEMM2 ---
  float sbreg[16];
  #pragma unroll
  for (int g = 0; g < 4; g++) {
    const int d_e = __shfl(dstR, g * 16 + lr);
    const int s_e = __shfl(srcR, g * 16 + lr);
    FragU A0, A1;
    {
      uint4 ua = *(const uint4*)(snbB + (size_t)d_e * 128 + 0 * 64 + lk * 16);
      uint4 ub = *(const uint4*)(snbB + (size_t)s_e * 128 + 0 * 64 + lk * 16);
      A0.u.x = __builtin_bit_cast(u32, __hsub2(as_h2(ua.x), as_h2(ub.x)));
      A0.u.y = __builtin_bit_cast(u32, __hsub2(as_h2(ua.y), as_h2(ub.y)));
      A0.u.z = __builtin_bit_cast(u32, __hsub2(as_h2(ua.z), as_h2(ub.z)));
      A0.u.w = __builtin_bit_cast(u32, __hsub2(as_h2(ua.w), as_h2(ub.w)));
      uint4 uc = *(const uint4*)(snbB + (size_t)d_e * 128 + 1 * 64 + lk * 16);
      uint4 ud = *(const uint4*)(snbB + (size_t)s_e * 128 + 1 * 64 + lk * 16);
      A1.u.x = __builtin_bit_cast(u32, __hsub2(as_h2(uc.x), as_h2(ud.x)));
      A1.u.y = __builtin_bit_cast(u32, __hsub2(as_h2(uc.y), as_h2(ud.y)));
      A1.u.z = __builtin_bit_cast(u32, __hsub2(as_h2(uc.z), as_h2(ud.z)));
      A1.u.w = __builtin_bit_cast(u32, __hsub2(as_h2(uc.w), as_h2(ud.w)));
    }
    f32x4 acc2 = { b2v, b2v, b2v, b2v };
    #pragma unroll
    for (int jt = 0; jt < 4; jt++) {
      FragU Bf0, Bf1;
      Bf0.u = sWs1F[(jt * 2 + 0) * 64 + lane];
      Bf1.u = sWs1F[(jt * 2 + 1) * 64 + lane];
      f32x4 acc = { b1v[jt], b1v[jt], b1v[jt], b1v[jt] };
      acc = __builtin_amdgcn_mfma_f32_16x16x32_f16(A0.v, Bf0.v, acc, 0, 0, 0);
      acc = __builtin_amdgcn_mfma_f32_16x16x32_f16(A1.v, Bf1.v, acc, 0, 0, 0);
      #pragma unroll
      for (int r = 0; r < 4; r++) {
        float gg = gelu_fast(acc[r]);
        h1lds[wid][lk * 4 + r][jt * 16 + lr] = __builtin_bit_cast(u16, (_Float16)gg);
      }
    }
    #pragma unroll
    for (int tk = 0; tk < 2; tk++) {
      FragU A2, B2f;
      A2.u = *(const uint4*)&h1lds[wid][lr][tk * 32 + lk * 8];
      if (lr < 8) B2f.u = sWs2F[tk * 32 + lk * 8 + lr];
      else        B2f.u = make_uint4(0, 0, 0, 0);
      acc2 = __builtin_amdgcn_mfma_f32_16x16x32_f16(A2.v, B2f.v, acc2, 0, 0, 0);
    }
    #pragma unroll
    for (int jt = 4; jt < 8; jt++) {
      FragU Bf0, Bf1;
      Bf0.u = sWs1F[(jt * 2 + 0) * 64 + lane];
      Bf1.u = sWs1F[(jt * 2 + 1) * 64 + lane];
      f32x4 acc = { b1v[jt], b1v[jt], b1v[jt], b1v[jt] };
      acc = __builtin_amdgcn_mfma_f32_16x16x32_f16(A0.v, Bf0.v, acc, 0, 0, 0);
      acc = __builtin_amdgcn_mfma_f32_16x16x32_f16(A1.v, Bf1.v, acc, 0, 0, 0);
      #pragma unroll
      for (int r = 0; r < 4; r++) {
        float gg = gelu_fast(acc[r]);
        h1lds[wid][lk * 4 + r][(jt - 4) * 16 + lr] = __builtin_bit_cast(u16, (_Float16)gg);
      }
    }
    #pragma unroll
    for (int tk = 2; tk < 4; tk++) {
      FragU A2, B2f;
      A2.u = *(const uint4*)&h1lds[wid][lr][(tk - 2) * 32 + lk * 8];
      if (lr < 8) B2f.u = sWs2F[tk * 32 + lk * 8 + lr];
      else        B2f.u = make_uint4(0, 0, 0, 0);
      acc2 = __builtin_amdgcn_mfma_f32_16x16x32_f16(A2.v, B2f.v, acc2, 0, 0, 0);
    }
    #pragma unroll
    for (int r = 0; r < 4; r++) sbreg[g * 4 + r] = acc2[r];
  }

  // --- sb redistribution through h1lds (wave-private reuse) ---
  u16* sbuf = &h1lds[wid][0][0];
  if (lr < 8) {
    #pragma unroll
    for (int g = 0; g < 4; g++)
      #pragma unroll
      for (int r = 0; r < 4; r++)
        sbuf[(g * 16 + lk * 4 + r) * 8 + lr] =
            __builtin_bit_cast(u16, (_Float16)sbreg[g * 4 + r]);
  }

  // --- phase B: thread-per-slot ---
  const int src = srcR;
  const int dst = dstR;

  float m[8];
  {
    uint4 mm = mtab[eR];        // 16 B scattered, L3-resident table
    u32 wv[4] = {mm.x, mm.y, mm.z, mm.w};
    #pragma unroll
    for (int q = 0; q < 4; q++) {
      m[2*q]   = h2_lo(as_h2(wv[q]));
      m[2*q+1] = h2_hi(as_h2(wv[q]));
    }
  }

  float tv[8];
  {
    uint4 sb4 = ((const uint4*)sbuf)[lane];
    u32 wv[4] = {sb4.x, sb4.y, sb4.z, sb4.w};
    #pragma unroll
    for (int q = 0; q < 4; q++) {
      tv[2*q]   = tanh_fast(h2_lo(as_h2(wv[q])));
      tv[2*q+1] = tanh_fast(h2_hi(as_h2(wv[q])));
    }
  }

  {
    const uint4* qp4 = (const uint4*)(qb + (size_t)dst * 128);
    const uint4* kp4 = (const uint4*)(kb + (size_t)src * 128);
    float ex[8];
    #pragma unroll
    for (int h = 0; h < 8; h++) {
      uint4 qa = qp4[2*h], qc = qp4[2*h+1];
      uint4 ka = kp4[2*h], kc = kp4[2*h+1];
      __half2 d2 = __floats2half2_rn(0.f, 0.f);
      d2 = __hfma2(as_h2(qa.x), as_h2(ka.x), d2);
      d2 = __hfma2(as_h2(qa.y), as_h2(ka.y), d2);
      d2 = __hfma2(as_h2(qa.z), as_h2(ka.z), d2);
      d2 = __hfma2(as_h2(qa.w), as_h2(ka.w), d2);
      d2 = __hfma2(as_h2(qc.x), as_h2(kc.x), d2);
      d2 = __hfma2(as_h2(qc.y), as_h2(kc.y), d2);
      d2 = __hfma2(as_h2(qc.z), as_h2(kc.z), d2);
      d2 = __hfma2(as_h2(qc.w), as_h2(kc.w), d2);
      float dot = h2_lo(d2) + h2_hi(d2);
      float logit = dot * 0.25f + m[h] + 0.1f * tv[h];
      ex[h] = __expf(logit);
    }
    uint4 st;
    st.x = (u32)f2bf(ex[0]) | ((u32)f2bf(ex[1]) << 16);
    st.y = (u32)f2bf(ex[2]) | ((u32)f2bf(ex[3]) << 16);
    st.z = (u32)f2bf(ex[4]) | ((u32)f2bf(ex[5]) << 16);
    st.w = (u32)f2bf(ex[6]) | ((u32)f2bf(ex[7]) << 16);
    exw[ibase + lane] = st;    // coalesced, CSR-ordered
  }
}

// ---------- kernel 3: wave-per-node CSR aggregate (8-deep) + gelu + residual ----------
__global__ __launch_bounds__(256) void aggregate_k(
    const int* __restrict__ offs, const int* __restrict__ deg,
    const int* __restrict__ psrc, const u32* __restrict__ exw,
    const u32* __restrict__ vb32, const float* __restrict__ x,
    float* __restrict__ out)
{
  const int n = (blockIdx.x * 256 + threadIdx.x) >> 6;   // wave per node
  const int lane = threadIdx.x & 63;
  if (n >= NN) return;
  const int s = offs[n];
  const int end = s + deg[n];
  const int word  = lane >> 4;
  const int shift = ((lane >> 3) & 1) << 4;

  float s0 = 0.f, s1 = 0.f, dn = 0.f;
  int i = s;
  for (; i + 8 <= end; i += 8) {
    int  pp[8]; u32 kk[8]; u32 vv[8];
    #pragma unroll
    for (int q = 0; q < 8; q++) pp[q] = psrc[i + q];
    #pragma unroll
    for (int q = 0; q < 8; q++) kk[q] = exw[(size_t)(i + q) * 4 + word];
    #pragma unroll
    for (int q = 0; q < 8; q++) vv[q] = vb32[(size_t)pp[q] * 64 + lane];
    #pragma unroll
    for (int q = 0; q < 8; q++) {
      float ex = __uint_as_float(((kk[q] >> shift) & 0xffffu) << 16);
      s0 = fmaf(bf_lo(vv[q]), ex, s0);
      s1 = fmaf(bf_hi(vv[q]), ex, s1);
      dn += ex;
    }
  }
  for (; i < end; i++) {
    int sp = psrc[i];
    u32 pkv = exw[(size_t)i * 4 + word];
    float ex = __uint_as_float(((pkv >> shift) & 0xffffu) << 16);
    u32 vv = vb32[(size_t)sp * 64 + lane];
    s0 = fmaf(bf_lo(vv), ex, s0);
    s1 = fmaf(bf_hi(vv), ex, s1);
    dn += ex;
  }
  float inv = 1.0f / (dn + 1e-12f);
  float2 xx = *(const float2*)(x + (size_t)n * 128 + lane * 2);
  float2 o;
  o.x = gelu_exact(s0 * inv) + xx.x;
  o.y = gelu_exact(s1 * inv) + xx.y;
  *(float2*)(out + (size_t)n * 128 + lane * 2) = o;
}

extern "C" void kernel_launch(void* const* d_in, const int* in_sizes, int n_in,
                              void* d_out, int out_size, void* d_ws, size_t ws_size,
                              hipStream_t stream)
{
  const float* x    = (const float*)d_in[0];
  const int*   ei   = (const int*)d_in[1];
  const float* ea   = (const float*)d_in[2];
  const float* seq  = (const float*)d_in[3];
  const float* ln_g = (const float*)d_in[4];
  const float* ln_b = (const float*)d_in[5];
  const float* Wq   = (const float*)d_in[6];
  const float* bq   = (const float*)d_in[7];
  const float* Wk   = (const float*)d_in[8];
  const float* bk   = (const float*)d_in[9];
  const float* Wv   = (const float*)d_in[10];
  const float* bv   = (const float*)d_in[11];
  const float* We0a = (const float*)d_in[12];
  const float* be0a = (const float*)d_in[13];
  const float* We0b = (const float*)d_in[14];
  const float* be0b = (const float*)d_in[15];
  const float* We1a = (const float*)d_in[16];
  const float* be1a = (const float*)d_in[17];
  const float* We1b = (const float*)d_in[18];
  const float* be1b = (const float*)d_in[19];
  const float* Ws1  = (const float*)d_in[20];
  const float* bs1  = (const float*)d_in[21];
  const float* Ws2  = (const float*)d_in[22];
  const float* bs2  = (const float*)d_in[23];
  float* out = (float*)d_out;

  // workspace layout (~81 MB)
  char* w = (char*)d_ws;
  __half* qb   = (__half*)w;                       w += (size_t)NN * 128 * 2;
  __half* kb   = (__half*)w;                       w += (size_t)NN * 128 * 2;
  u16*    vb   = (u16*)w;                          w += (size_t)NN * 128 * 2;
  __half* snb  = (__half*)w;                       w += (size_t)NN * 64 * 2;
  uint4*  exw  = (uint4*)w;                        w += (size_t)EE * 16;
  uint4*  mtab = (uint4*)w;                        w += (size_t)EE * 16;
  int*    psrc = (int*)w;                          w += (size_t)EE * 4;
  int*    pe   = (int*)w;                          w += (size_t)EE * 4;
  int*    dstOf= (int*)w;                          w += (size_t)EE * 4;
  int*    deg  = (int*)w;                          w += (size_t)NN * 4;
  int*    offs = (int*)w;                          w += (size_t)NN * 4;
  int*    cursor = (int*)w;                        w += (size_t)NN * 4;
  int*    csum = (int*)w;                          w += (size_t)NCHUNK * 4;
  int*    cbase = (int*)w;                         w += (size_t)NCHUNK * 4;

  (void)hipMemsetAsync(deg, 0, (size_t)NN * 4, stream);

  count_mlp_k<<<EE / 256, 256, 0, stream>>>(
      ei, ea, We0a, be0a, We0b, be0b, We1a, be1a, We1b, be1b, deg, mtab);
  chunksum_k<<<NCHUNK / 4, 256, 0, stream>>>(deg, csum);
  chunkscan_k<<<1, 64, 0, stream>>>(csum, cbase);
  writeoffs_k<<<NCHUNK / 4, 256, 0, stream>>>(deg, cbase, offs, cursor);
  scatter_pairs_k<<<EE / 256, 256, 0, stream>>>(ei, cursor, psrc, pe, dstOf);

  node_pre<<<(NN + 63) / 64, 512, 0, stream>>>(
      x, seq, ln_g, ln_b, Wq, bq, Wk, bk, Wv, bv, qb, kb, vb, snb);

  edge_fused<<<EE / 256, 256, 0, stream>>>(
      mtab, qb, kb, snb, psrc, pe, dstOf,
      Ws1, bs1, Ws2, bs2, exw);

  aggregate_k<<<(NN * 64) / 256, 256, 0, stream>>>(
      offs, deg, psrc, (const u32*)exw, (const u32*)vb, x, out);
}

// Round 21
// 284.981 us; speedup vs baseline: 1.0714x; 1.0276x over previous
//
#include <hip/hip_runtime.h>
#include <hip/hip_fp16.h>

#define NN 50000
#define EE 800000
#define NCHUNK 784          // 784 chunks of 64 nodes = 50176 >= NN
#define NEB 1563            // edge blocks in fusedA: 1563*512 = 800256 >= EE
#define NNB 782             // node blocks in fusedA: 782*64 = 50048 >= NN

typedef unsigned int u32;
typedef unsigned short u16;
typedef _Float16 f16x8 __attribute__((ext_vector_type(8)));
typedef float f32x4 __attribute__((ext_vector_type(4)));

// ---------- helpers ----------
__device__ __forceinline__ float bf_lo(u32 u){ return __uint_as_float(u << 16); }
__device__ __forceinline__ float bf_hi(u32 u){ return __uint_as_float(u & 0xffff0000u); }
__device__ __forceinline__ u16 f2bf(float f){
  u32 x = __float_as_uint(f);
  x += 0x7fffu + ((x >> 16) & 1u);       // RNE
  return (u16)(x >> 16);
}
__device__ __forceinline__ float gelu_exact(float x){
  return x * 0.5f * (1.0f + erff(x * 0.70710678118654752f));
}
__device__ __forceinline__ float rcp_fast(float x){ return __builtin_amdgcn_rcpf(x); }
__device__ __forceinline__ float gelu_fast(float x){
  float x2 = x * x;
  float y  = x * fmaf(x2, 0.0356774081f, 0.7978845608f);
  float e  = __expf(y + y);
  return x - x * rcp_fast(e + 1.0f);
}
__device__ __forceinline__ float tanh_fast(float x){
  float e = __expf(x + x);
  return 1.0f - 2.0f * rcp_fast(e + 1.0f);
}
__device__ __forceinline__ int atomic_inc_i32(int* p){
  return __hip_atomic_fetch_add(p, 1, __ATOMIC_RELAXED, __HIP_MEMORY_SCOPE_AGENT);
}
__device__ __forceinline__ __half2 as_h2(u32 u){ return __builtin_bit_cast(__half2, u); }
__device__ __forceinline__ u32 pack2f(float a, float b){
  __half2 h = __floats2half2_rn(a, b);
  return __builtin_bit_cast(u32, h);
}
__device__ __forceinline__ float h2_lo(__half2 h){ return __half2float(__low2half(h)); }
__device__ __forceinline__ float h2_hi(__half2 h){ return __half2float(__high2half(h)); }

union FragU { uint4 u; f16x8 v; };

// shared-memory union for the co-launched kernel
union __align__(16) SmemA {
  u16 h16[64][136];                 // node part: 17408 B
  struct {
    u32 sWeah[2 * 264];
    u32 sWebTh[2 * 136];
    float sbea[64];
    float sbeb[16];
  } em;                             // edge part: ~3.5 KB
};

// ---------- kernel A: co-launched {degree count + edge-MLP} || {LN + QKV + seq-norm} ----------
__global__ __launch_bounds__(512) void fusedA(
    const int* __restrict__ ei, const float* __restrict__ edge_attr,
    const float* __restrict__ We0a, const float* __restrict__ be0a,
    const float* __restrict__ We0b, const float* __restrict__ be0b,
    const float* __restrict__ We1a, const float* __restrict__ be1a,
    const float* __restrict__ We1b, const float* __restrict__ be1b,
    int* __restrict__ deg, uint4* __restrict__ mtab,
    const float* __restrict__ x, const float* __restrict__ seq,
    const float* __restrict__ ln_g, const float* __restrict__ ln_b,
    const float* __restrict__ Wq, const float* __restrict__ bq,
    const float* __restrict__ Wk, const float* __restrict__ bk,
    const float* __restrict__ Wv, const float* __restrict__ bv,
    __half* __restrict__ qb, __half* __restrict__ kb,
    u16* __restrict__ vb, __half* __restrict__ snb)
{
  __shared__ SmemA sm;
  const int t = threadIdx.x;

  if (blockIdx.x < NEB) {
    // ================= edge part: degree count + edge-type MLP =================
    u32*   sWeah  = sm.em.sWeah;
    u32*   sWebTh = sm.em.sWebTh;
    float* sbea   = sm.em.sbea;
    float* sbeb   = sm.em.sbeb;

    for (int idx = t; idx < 512; idx += 512) {
      int e2 = idx >> 8, rem = idx & 255, j = rem >> 3, q = rem & 7;
      const float* W = e2 ? We1a : We0a;
      sWeah[e2 * 264 + rem] = pack2f(W[j * 16 + 2 * q], W[j * 16 + 2 * q + 1]);
    }
    if (t < 256) {
      int e2 = t >> 7, rem = t & 127, j = rem >> 2, q = rem & 3;
      const float* W = e2 ? We1b : We0b;
      sWebTh[e2 * 136 + rem] = pack2f(W[(2 * q) * 32 + j], W[(2 * q + 1) * 32 + j]);
    }
    if (t < 64) sbea[t] = (t < 32) ? be0a[t] : be1a[t - 32];
    if (t < 16) sbeb[t] = (t < 8) ? be0b[t] : be1b[t - 8];
    __syncthreads();

    const int e = blockIdx.x * 512 + t;
    if (e < EE) {
      atomic_inc_i32(&deg[ei[EE + e]]);

      __half2 ef2[8]; float a16, a17;
      {
        const float2* p2 = (const float2*)(edge_attr + (size_t)e * 18);
        float2 p[9];
        #pragma unroll
        for (int i = 0; i < 9; i++) p[i] = p2[i];
        #pragma unroll
        for (int i = 0; i < 8; i++) ef2[i] = __floats2half2_rn(p[i].x, p[i].y);
        a16 = p[8].x; a17 = p[8].y;
      }
      const int sel = (a17 > a16) ? 1 : 0;
      const u32* Wah = sWeah + sel * 264;
      const u32* Wbh = sWebTh + sel * 136;
      const float* ba = sbea + sel * 32;
      const float* bb = sbeb + sel * 8;

      __half2 m2[4];
      #pragma unroll
      for (int q = 0; q < 4; q++) m2[q] = __floats2half2_rn(bb[2 * q], bb[2 * q + 1]);
      for (int j = 0; j < 32; j++) {
        __half2 a = __floats2half2_rn(0.f, 0.f);
        #pragma unroll
        for (int q = 0; q < 8; q++) a = __hfma2(as_h2(Wah[j * 8 + q]), ef2[q], a);
        float hs = h2_lo(a) + h2_hi(a) + ba[j];
        hs = fmaxf(hs, 0.f);
        __half2 hs2 = __float2half2_rn(hs);
        #pragma unroll
        for (int q = 0; q < 4; q++) m2[q] = __hfma2(as_h2(Wbh[j * 4 + q]), hs2, m2[q]);
      }
      uint4 st;
      st.x = __builtin_bit_cast(u32, m2[0]);
      st.y = __builtin_bit_cast(u32, m2[1]);
      st.z = __builtin_bit_cast(u32, m2[2]);
      st.w = __builtin_bit_cast(u32, m2[3]);
      mtab[e] = st;
    }
    return;
  }

  // ================= node part: LN + seq-normalize + MFMA QKV =================
  const int nbase = (blockIdx.x - NEB) * 64;
  {
    const int row = t >> 3, sub = t & 7;
    const int n = nbase + row;
    if (n < NN) {
      const float* xp = x + (size_t)n * 128 + sub * 16;
      float vals[16];
      float s = 0.f, ss = 0.f;
      #pragma unroll
      for (int j = 0; j < 16; j += 4) {
        float4 v4 = *(const float4*)(xp + j);
        vals[j] = v4.x; vals[j+1] = v4.y; vals[j+2] = v4.z; vals[j+3] = v4.w;
        s += v4.x + v4.y + v4.z + v4.w;
        ss += v4.x*v4.x + v4.y*v4.y + v4.z*v4.z + v4.w*v4.w;
      }
      #pragma unroll
      for (int o = 1; o < 8; o <<= 1) { s += __shfl_xor(s, o); ss += __shfl_xor(ss, o); }
      float mu = s * (1.f / 128.f);
      float var = ss * (1.f / 128.f) - mu * mu;
      float rs = rsqrtf(var + 1e-5f);
      #pragma unroll
      for (int j = 0; j < 16; j += 2) {
        int c = sub * 16 + j;
        float v0 = (vals[j]   - mu) * rs * ln_g[c]   + ln_b[c];
        float v1 = (vals[j+1] - mu) * rs * ln_g[c+1] + ln_b[c+1];
        *(u32*)&sm.h16[row][c] = pack2f(v0, v1);
      }
      const float* sp = seq + (size_t)n * 64 + sub * 8;
      float4 a = *(const float4*)(sp);
      float4 b4 = *(const float4*)(sp + 4);
      float q2 = a.x*a.x + a.y*a.y + a.z*a.z + a.w*a.w
               + b4.x*b4.x + b4.y*b4.y + b4.z*b4.z + b4.w*b4.w;
      #pragma unroll
      for (int o = 1; o < 8; o <<= 1) q2 += __shfl_xor(q2, o);
      float inv = 1.0f / fmaxf(sqrtf(q2), 1e-12f);
      __half* op = snb + (size_t)n * 64 + sub * 8;
      op[0]=__float2half(a.x*inv);  op[1]=__float2half(a.y*inv);
      op[2]=__float2half(a.z*inv);  op[3]=__float2half(a.w*inv);
      op[4]=__float2half(b4.x*inv); op[5]=__float2half(b4.y*inv);
      op[6]=__float2half(b4.z*inv); op[7]=__float2half(b4.w*inv);
    }
  }

  const int lane = t & 63, wid = t >> 6;
  const int lr = lane & 15;
  const int lk = lane >> 4;
  const int tile0 = wid * 3;

  FragU Bf[3][4];
  float bias[3];
  #pragma unroll
  for (int ti = 0; ti < 3; ti++) {
    int tile = tile0 + ti;
    int mat = tile >> 3;
    int colm = (tile & 7) * 16 + lr;
    const float* W = (mat == 0) ? Wq : (mat == 1) ? Wk : Wv;
    const float* B = (mat == 0) ? bq : (mat == 1) ? bk : bv;
    bias[ti] = B[colm];
    const float* wrow = W + (size_t)colm * 128;
    #pragma unroll
    for (int ks = 0; ks < 4; ks++) {
      const float* wp = wrow + ks * 32 + lk * 8;
      float4 wa = *(const float4*)(wp);
      float4 wb = *(const float4*)(wp + 4);
      Bf[ti][ks].u.x = pack2f(wa.x, wa.y);
      Bf[ti][ks].u.y = pack2f(wa.z, wa.w);
      Bf[ti][ks].u.z = pack2f(wb.x, wb.y);
      Bf[ti][ks].u.w = pack2f(wb.z, wb.w);
    }
  }
  __syncthreads();

  #pragma unroll
  for (int mt = 0; mt < 4; mt++) {
    FragU A[4];
    #pragma unroll
    for (int ks = 0; ks < 4; ks++)
      A[ks].u = *(const uint4*)&sm.h16[mt * 16 + lr][ks * 32 + lk * 8];
    #pragma unroll
    for (int ti = 0; ti < 3; ti++) {
      f32x4 acc = { bias[ti], bias[ti], bias[ti], bias[ti] };
      #pragma unroll
      for (int ks = 0; ks < 4; ks++)
        acc = __builtin_amdgcn_mfma_f32_16x16x32_f16(A[ks].v, Bf[ti][ks].v, acc, 0, 0, 0);
      int tile = tile0 + ti;
      int mat = tile >> 3;
      int colm = (tile & 7) * 16 + lr;
      __half* Oh = (mat == 0) ? qb : kb;
      #pragma unroll
      for (int r = 0; r < 4; r++) {
        int node = nbase + mt * 16 + lk * 4 + r;
        if (node < NN) {
          float val = acc[r];
          if (mat == 2) vb[(size_t)node * 128 + colm] = f2bf(val);
          else          Oh[(size_t)node * 128 + colm] = __float2half(val);
        }
      }
    }
  }
}

// ---------- CSR build ----------
__global__ __launch_bounds__(256) void chunksum_k(const int* __restrict__ deg, int* __restrict__ csum)
{
  const int c = blockIdx.x * 4 + (threadIdx.x >> 6);
  const int lane = threadIdx.x & 63;
  const int idx = c * 64 + lane;
  int v = (idx < NN) ? deg[idx] : 0;
  #pragma unroll
  for (int o = 1; o < 64; o <<= 1) v += __shfl_xor(v, o);
  if (lane == 0) csum[c] = v;
}

__global__ __launch_bounds__(64) void chunkscan_k(const int* __restrict__ csum, int* __restrict__ cbase)
{
  const int lane = threadIdx.x;
  const int CH = 13;
  const int base = lane * CH;
  int s = 0;
  #pragma unroll
  for (int j = 0; j < CH; j++) {
    int c = base + j;
    s += (c < NCHUNK) ? csum[c] : 0;
  }
  int inc = s;
  #pragma unroll
  for (int off = 1; off < 64; off <<= 1) {
    int v = __shfl_up(inc, off);
    if (lane >= off) inc += v;
  }
  int run = inc - s;
  #pragma unroll
  for (int j = 0; j < CH; j++) {
    int c = base + j;
    if (c < NCHUNK) {
      cbase[c] = run;
      run += csum[c];
    }
  }
}

__global__ __launch_bounds__(256) void writeoffs_k(
    const int* __restrict__ deg, const int* __restrict__ cbase,
    int* __restrict__ offs, int* __restrict__ cursor)
{
  const int c = blockIdx.x * 4 + (threadIdx.x >> 6);
  const int lane = threadIdx.x & 63;
  const int idx = c * 64 + lane;
  int d = (idx < NN) ? deg[idx] : 0;
  int inc = d;
  #pragma unroll
  for (int off = 1; off < 64; off <<= 1) {
    int v = __shfl_up(inc, off);
    if (lane >= off) inc += v;
  }
  int off_ = cbase[c] + inc - d;
  if (idx < NN) {
    offs[idx] = off_;
    cursor[idx] = off_;
  }
}

// CSR-ordered arrays: psrc (src node), pe (edge id), dstOf (dst node)
__global__ __launch_bounds__(256) void scatter_pairs_k(
    const int* __restrict__ ei, int* __restrict__ cursor,
    int* __restrict__ psrc, int* __restrict__ pe, int* __restrict__ dstOf)
{
  int e = blockIdx.x * 256 + threadIdx.x;
  int src = ei[e];
  int dst = ei[EE + e];
  int pos = atomic_inc_i32(&cursor[dst]);
  psrc[pos]  = src;
  pe[pos]    = e;
  dstOf[pos] = dst;
}

// ---------- kernel 2: FUSED, CSR-SLOT-ORDERED seq-MLP (MFMA) + mtab + QK + exp ----------
__global__ __launch_bounds__(256, 5) void edge_fused(
    const uint4* __restrict__ mtab,
    const __half* __restrict__ qb, const __half* __restrict__ kb,
    const __half* __restrict__ snb,
    const int* __restrict__ psrc, const int* __restrict__ pe,
    const int* __restrict__ dstOf,
    const float* __restrict__ Ws1, const float* __restrict__ bs1,
    const float* __restrict__ Ws2, const float* __restrict__ bs2,
    uint4* __restrict__ exw)
{
  __shared__ __align__(16) u16 h1lds[4][16][72];    // half-width h1 (+8 pad) / sb redistribution
  __shared__ __align__(16) uint4 sWs1F[1024];       // Ws1 frags (16 KB)
  __shared__ __align__(16) uint4 sWs2F[128];        // Ws2 frags (2 KB)

  const int t = threadIdx.x;
  const int lane = t & 63, wid = t >> 6;
  const int lr = lane & 15;
  const int lk = lane >> 4;
  const int ibase = blockIdx.x * 256 + wid * 64;    // CSR slot base for this wave

  // --- stage seq-MLP weight FRAGMENTS into LDS ---
  for (int fid = t; fid < 1024; fid += 256) {
    int lf = fid & 63, tk = (fid >> 6) & 1, jt = fid >> 7;
    int lrf = lf & 15, lkf = lf >> 4;
    const float* wp = Ws1 + (size_t)(jt * 16 + lrf) * 64 + tk * 32 + lkf * 8;
    float4 wa = *(const float4*)(wp);
    float4 wb = *(const float4*)(wp + 4);
    uint4 fr;
    fr.x = pack2f(wa.x, wa.y); fr.y = pack2f(wa.z, wa.w);
    fr.z = pack2f(wb.x, wb.y); fr.w = pack2f(wb.z, wb.w);
    sWs1F[fid] = fr;
  }
  if (t < 128) {
    int lrf = t & 7, lkf = (t >> 3) & 3, tk = t >> 5;
    const float* wp = Ws2 + (size_t)lrf * 128 + tk * 32 + lkf * 8;
    float4 wa = *(const float4*)(wp);
    float4 wb = *(const float4*)(wp + 4);
    uint4 fr;
    fr.x = pack2f(wa.x, wa.y); fr.y = pack2f(wa.z, wa.w);
    fr.z = pack2f(wb.x, wb.y); fr.w = pack2f(wb.z, wb.w);
    sWs2F[t] = fr;
  }

  float b1v[8];
  #pragma unroll
  for (int jt = 0; jt < 8; jt++) b1v[jt] = bs1[jt * 16 + lr];
  const float b2v = (lr < 8) ? bs2[lr] : 0.f;

  const int srcR = psrc[ibase + lane];     // coalesced
  const int dstR = dstOf[ibase + lane];    // coalesced, ~segment-constant
  const int eR   = pe[ibase + lane];       // coalesced read, random values
  const char* snbB = (const char*)snb;

  __syncthreads();

  // --- phase A: seq-MLP (MFMA), 4 groups of 16 slots; split GEMM2 ---
  float sbreg[16];
  #pragma unroll
  for (int g = 0; g < 4; g++) {
    const int d_e = __shfl(dstR, g * 16 + lr);
    const int s_e = __shfl(srcR, g * 16 + lr);
    FragU A0, A1;
    {
      uint4 ua = *(const uint4*)(snbB + (size_t)d_e * 128 + 0 * 64 + lk * 16);
      uint4 ub = *(const uint4*)(snbB + (size_t)s_e * 128 + 0 * 64 + lk * 16);
      A0.u.x = __builtin_bit_cast(u32, __hsub2(as_h2(ua.x), as_h2(ub.x)));
      A0.u.y = __builtin_bit_cast(u32, __hsub2(as_h2(ua.y), as_h2(ub.y)));
      A0.u.z = __builtin_bit_cast(u32, __hsub2(as_h2(ua.z), as_h2(ub.z)));
      A0.u.w = __builtin_bit_cast(u32, __hsub2(as_h2(ua.w), as_h2(ub.w)));
      uint4 uc = *(const uint4*)(snbB + (size_t)d_e * 128 + 1 * 64 + lk * 16);
      uint4 ud = *(const uint4*)(snbB + (size_t)s_e * 128 + 1 * 64 + lk * 16);
      A1.u.x = __builtin_bit_cast(u32, __hsub2(as_h2(uc.x), as_h2(ud.x)));
      A1.u.y = __builtin_bit_cast(u32, __hsub2(as_h2(uc.y), as_h2(ud.y)));
      A1.u.z = __builtin_bit_cast(u32, __hsub2(as_h2(uc.z), as_h2(ud.z)));
      A1.u.w = __builtin_bit_cast(u32, __hsub2(as_h2(uc.w), as_h2(ud.w)));
    }
    f32x4 acc2 = { b2v, b2v, b2v, b2v };
    #pragma unroll
    for (int jt = 0; jt < 4; jt++) {
      FragU Bf0, Bf1;
      Bf0.u = sWs1F[(jt * 2 + 0) * 64 + lane];
      Bf1.u = sWs1F[(jt * 2 + 1) * 64 + lane];
      f32x4 acc = { b1v[jt], b1v[jt], b1v[jt], b1v[jt] };
      acc = __builtin_amdgcn_mfma_f32_16x16x32_f16(A0.v, Bf0.v, acc, 0, 0, 0);
      acc = __builtin_amdgcn_mfma_f32_16x16x32_f16(A1.v, Bf1.v, acc, 0, 0, 0);
      #pragma unroll
      for (int r = 0; r < 4; r++) {
        float gg = gelu_fast(acc[r]);
        h1lds[wid][lk * 4 + r][jt * 16 + lr] = __builtin_bit_cast(u16, (_Float16)gg);
      }
    }
    #pragma unroll
    for (int tk = 0; tk < 2; tk++) {
      FragU A2, B2f;
      A2.u = *(const uint4*)&h1lds[wid][lr][tk * 32 + lk * 8];
      if (lr < 8) B2f.u = sWs2F[tk * 32 + lk * 8 + lr];
      else        B2f.u = make_uint4(0, 0, 0, 0);
      acc2 = __builtin_amdgcn_mfma_f32_16x16x32_f16(A2.v, B2f.v, acc2, 0, 0, 0);
    }
    #pragma unroll
    for (int jt = 4; jt < 8; jt++) {
      FragU Bf0, Bf1;
      Bf0.u = sWs1F[(jt * 2 + 0) * 64 + lane];
      Bf1.u = sWs1F[(jt * 2 + 1) * 64 + lane];
      f32x4 acc = { b1v[jt], b1v[jt], b1v[jt], b1v[jt] };
      acc = __builtin_amdgcn_mfma_f32_16x16x32_f16(A0.v, Bf0.v, acc, 0, 0, 0);
      acc = __builtin_amdgcn_mfma_f32_16x16x32_f16(A1.v, Bf1.v, acc, 0, 0, 0);
      #pragma unroll
      for (int r = 0; r < 4; r++) {
        float gg = gelu_fast(acc[r]);
        h1lds[wid][lk * 4 + r][(jt - 4) * 16 + lr] = __builtin_bit_cast(u16, (_Float16)gg);
      }
    }
    #pragma unroll
    for (int tk = 2; tk < 4; tk++) {
      FragU A2, B2f;
      A2.u = *(const uint4*)&h1lds[wid][lr][(tk - 2) * 32 + lk * 8];
      if (lr < 8) B2f.u = sWs2F[tk * 32 + lk * 8 + lr];
      else        B2f.u = make_uint4(0, 0, 0, 0);
      acc2 = __builtin_amdgcn_mfma_f32_16x16x32_f16(A2.v, B2f.v, acc2, 0, 0, 0);
    }
    #pragma unroll
    for (int r = 0; r < 4; r++) sbreg[g * 4 + r] = acc2[r];
  }

  // --- sb redistribution through h1lds (wave-private reuse) ---
  u16* sbuf = &h1lds[wid][0][0];
  if (lr < 8) {
    #pragma unroll
    for (int g = 0; g < 4; g++)
      #pragma unroll
      for (int r = 0; r < 4; r++)
        sbuf[(g * 16 + lk * 4 + r) * 8 + lr] =
            __builtin_bit_cast(u16, (_Float16)sbreg[g * 4 + r]);
  }

  // --- phase B: thread-per-slot ---
  const int src = srcR;
  const int dst = dstR;

  float m[8];
  {
    uint4 mm = mtab[eR];        // 16 B scattered, L3-resident table
    u32 wv[4] = {mm.x, mm.y, mm.z, mm.w};
    #pragma unroll
    for (int q = 0; q < 4; q++) {
      m[2*q]   = h2_lo(as_h2(wv[q]));
      m[2*q+1] = h2_hi(as_h2(wv[q]));
    }
  }

  float tv[8];
  {
    uint4 sb4 = ((const uint4*)sbuf)[lane];
    u32 wv[4] = {sb4.x, sb4.y, sb4.z, sb4.w};
    #pragma unroll
    for (int q = 0; q < 4; q++) {
      tv[2*q]   = tanh_fast(h2_lo(as_h2(wv[q])));
      tv[2*q+1] = tanh_fast(h2_hi(as_h2(wv[q])));
    }
  }

  {
    const uint4* qp4 = (const uint4*)(qb + (size_t)dst * 128);
    const uint4* kp4 = (const uint4*)(kb + (size_t)src * 128);
    float ex[8];
    #pragma unroll
    for (int h = 0; h < 8; h++) {
      uint4 qa = qp4[2*h], qc = qp4[2*h+1];
      uint4 ka = kp4[2*h], kc = kp4[2*h+1];
      __half2 d2 = __floats2half2_rn(0.f, 0.f);
      d2 = __hfma2(as_h2(qa.x), as_h2(ka.x), d2);
      d2 = __hfma2(as_h2(qa.y), as_h2(ka.y), d2);
      d2 = __hfma2(as_h2(qa.z), as_h2(ka.z), d2);
      d2 = __hfma2(as_h2(qa.w), as_h2(ka.w), d2);
      d2 = __hfma2(as_h2(qc.x), as_h2(kc.x), d2);
      d2 = __hfma2(as_h2(qc.y), as_h2(kc.y), d2);
      d2 = __hfma2(as_h2(qc.z), as_h2(kc.z), d2);
      d2 = __hfma2(as_h2(qc.w), as_h2(kc.w), d2);
      float dot = h2_lo(d2) + h2_hi(d2);
      float logit = dot * 0.25f + m[h] + 0.1f * tv[h];
      ex[h] = __expf(logit);
    }
    uint4 st;
    st.x = (u32)f2bf(ex[0]) | ((u32)f2bf(ex[1]) << 16);
    st.y = (u32)f2bf(ex[2]) | ((u32)f2bf(ex[3]) << 16);
    st.z = (u32)f2bf(ex[4]) | ((u32)f2bf(ex[5]) << 16);
    st.w = (u32)f2bf(ex[6]) | ((u32)f2bf(ex[7]) << 16);
    exw[ibase + lane] = st;    // coalesced, CSR-ordered
  }
}

// ---------- kernel 3: wave-per-node CSR aggregate (8-deep) + gelu + residual ----------
__global__ __launch_bounds__(256) void aggregate_k(
    const int* __restrict__ offs, const int* __restrict__ deg,
    const int* __restrict__ psrc, const u32* __restrict__ exw,
    const u32* __restrict__ vb32, const float* __restrict__ x,
    float* __restrict__ out)
{
  const int n = (blockIdx.x * 256 + threadIdx.x) >> 6;   // wave per node
  const int lane = threadIdx.x & 63;
  if (n >= NN) return;
  const int s = offs[n];
  const int end = s + deg[n];
  const int word  = lane >> 4;
  const int shift = ((lane >> 3) & 1) << 4;

  float s0 = 0.f, s1 = 0.f, dn = 0.f;
  int i = s;
  for (; i + 8 <= end; i += 8) {
    int  pp[8]; u32 kk[8]; u32 vv[8];
    #pragma unroll
    for (int q = 0; q < 8; q++) pp[q] = psrc[i + q];
    #pragma unroll
    for (int q = 0; q < 8; q++) kk[q] = exw[(size_t)(i + q) * 4 + word];
    #pragma unroll
    for (int q = 0; q < 8; q++) vv[q] = vb32[(size_t)pp[q] * 64 + lane];
    #pragma unroll
    for (int q = 0; q < 8; q++) {
      float ex = __uint_as_float(((kk[q] >> shift) & 0xffffu) << 16);
      s0 = fmaf(bf_lo(vv[q]), ex, s0);
      s1 = fmaf(bf_hi(vv[q]), ex, s1);
      dn += ex;
    }
  }
  for (; i < end; i++) {
    int sp = psrc[i];
    u32 pkv = exw[(size_t)i * 4 + word];
    float ex = __uint_as_float(((pkv >> shift) & 0xffffu) << 16);
    u32 vv = vb32[(size_t)sp * 64 + lane];
    s0 = fmaf(bf_lo(vv), ex, s0);
    s1 = fmaf(bf_hi(vv), ex, s1);
    dn += ex;
  }
  float inv = 1.0f / (dn + 1e-12f);
  float2 xx = *(const float2*)(x + (size_t)n * 128 + lane * 2);
  float2 o;
  o.x = gelu_exact(s0 * inv) + xx.x;
  o.y = gelu_exact(s1 * inv) + xx.y;
  *(float2*)(out + (size_t)n * 128 + lane * 2) = o;
}

extern "C" void kernel_launch(void* const* d_in, const int* in_sizes, int n_in,
                              void* d_out, int out_size, void* d_ws, size_t ws_size,
                              hipStream_t stream)
{
  const float* x    = (const float*)d_in[0];
  const int*   ei   = (const int*)d_in[1];
  const float* ea   = (const float*)d_in[2];
  const float* seq  = (const float*)d_in[3];
  const float* ln_g = (const float*)d_in[4];
  const float* ln_b = (const float*)d_in[5];
  const float* Wq   = (const float*)d_in[6];
  const float* bq   = (const float*)d_in[7];
  const float* Wk   = (const float*)d_in[8];
  const float* bk   = (const float*)d_in[9];
  const float* Wv   = (const float*)d_in[10];
  const float* bv   = (const float*)d_in[11];
  const float* We0a = (const float*)d_in[12];
  const float* be0a = (const float*)d_in[13];
  const float* We0b = (const float*)d_in[14];
  const float* be0b = (const float*)d_in[15];
  const float* We1a = (const float*)d_in[16];
  const float* be1a = (const float*)d_in[17];
  const float* We1b = (const float*)d_in[18];
  const float* be1b = (const float*)d_in[19];
  const float* Ws1  = (const float*)d_in[20];
  const float* bs1  = (const float*)d_in[21];
  const float* Ws2  = (const float*)d_in[22];
  const float* bs2  = (const float*)d_in[23];
  float* out = (float*)d_out;

  // workspace layout (~81 MB)
  char* w = (char*)d_ws;
  __half* qb   = (__half*)w;                       w += (size_t)NN * 128 * 2;
  __half* kb   = (__half*)w;                       w += (size_t)NN * 128 * 2;
  u16*    vb   = (u16*)w;                          w += (size_t)NN * 128 * 2;
  __half* snb  = (__half*)w;                       w += (size_t)NN * 64 * 2;
  uint4*  exw  = (uint4*)w;                        w += (size_t)EE * 16;
  uint4*  mtab = (uint4*)w;                        w += (size_t)EE * 16;
  int*    psrc = (int*)w;                          w += (size_t)EE * 4;
  int*    pe   = (int*)w;                          w += (size_t)EE * 4;
  int*    dstOf= (int*)w;                          w += (size_t)EE * 4;
  int*    deg  = (int*)w;                          w += (size_t)NN * 4;
  int*    offs = (int*)w;                          w += (size_t)NN * 4;
  int*    cursor = (int*)w;                        w += (size_t)NN * 4;
  int*    csum = (int*)w;                          w += (size_t)NCHUNK * 4;
  int*    cbase = (int*)w;                         w += (size_t)NCHUNK * 4;

  (void)hipMemsetAsync(deg, 0, (size_t)NN * 4, stream);

  fusedA<<<NEB + NNB, 512, 0, stream>>>(
      ei, ea, We0a, be0a, We0b, be0b, We1a, be1a, We1b, be1b, deg, mtab,
      x, seq, ln_g, ln_b, Wq, bq, Wk, bk, Wv, bv, qb, kb, vb, snb);

  chunksum_k<<<NCHUNK / 4, 256, 0, stream>>>(deg, csum);
  chunkscan_k<<<1, 64, 0, stream>>>(csum, cbase);
  writeoffs_k<<<NCHUNK / 4, 256, 0, stream>>>(deg, cbase, offs, cursor);
  scatter_pairs_k<<<EE / 256, 256, 0, stream>>>(ei, cursor, psrc, pe, dstOf);

  edge_fused<<<EE / 256, 256, 0, stream>>>(
      mtab, qb, kb, snb, psrc, pe, dstOf,
      Ws1, bs1, Ws2, bs2, exw);

  aggregate_k<<<(NN * 64) / 256, 256, 0, stream>>>(
      offs, deg, psrc, (const u32*)exw, (const u32*)vb, x, out);
}

// Round 23
// 282.415 us; speedup vs baseline: 1.0811x; 1.0091x over previous
//
#include <hip/hip_runtime.h>
#include <hip/hip_fp16.h>

#define NN 50000
#define EE 800000
#define NCHUNK 784          // 784 chunks of 64 nodes = 50176 >= NN
#define NEB 1563            // edge blocks in fusedA: 1563*512 = 800256 >= EE
#define NNB 782             // node blocks in fusedA: 782*64 = 50048 >= NN

typedef unsigned int u32;
typedef unsigned short u16;
typedef _Float16 f16x8 __attribute__((ext_vector_type(8)));
typedef float f32x4 __attribute__((ext_vector_type(4)));

// ---------- helpers ----------
__device__ __forceinline__ float bf_lo(u32 u){ return __uint_as_float(u << 16); }
__device__ __forceinline__ float bf_hi(u32 u){ return __uint_as_float(u & 0xffff0000u); }
__device__ __forceinline__ u16 f2bf(float f){
  u32 x = __float_as_uint(f);
  x += 0x7fffu + ((x >> 16) & 1u);       // RNE
  return (u16)(x >> 16);
}
__device__ __forceinline__ float gelu_exact(float x){
  return x * 0.5f * (1.0f + erff(x * 0.70710678118654752f));
}
__device__ __forceinline__ float rcp_fast(float x){ return __builtin_amdgcn_rcpf(x); }
__device__ __forceinline__ float gelu_fast(float x){
  float x2 = x * x;
  float y  = x * fmaf(x2, 0.0356774081f, 0.7978845608f);
  float e  = __expf(y + y);
  return x - x * rcp_fast(e + 1.0f);
}
__device__ __forceinline__ float tanh_fast(float x){
  float e = __expf(x + x);
  return 1.0f - 2.0f * rcp_fast(e + 1.0f);
}
__device__ __forceinline__ int atomic_inc_i32(int* p){
  return __hip_atomic_fetch_add(p, 1, __ATOMIC_RELAXED, __HIP_MEMORY_SCOPE_AGENT);
}
__device__ __forceinline__ __half2 as_h2(u32 u){ return __builtin_bit_cast(__half2, u); }
__device__ __forceinline__ u32 pack2f(float a, float b){
  __half2 h = __floats2half2_rn(a, b);
  return __builtin_bit_cast(u32, h);
}
__device__ __forceinline__ float h2_lo(__half2 h){ return __half2float(__low2half(h)); }
__device__ __forceinline__ float h2_hi(__half2 h){ return __half2float(__high2half(h)); }

union FragU { uint4 u; f16x8 v; };

// shared-memory union for the co-launched kernel
union __align__(16) SmemA {
  u16 h16[64][136];                 // node part: 17408 B
  struct {
    u32 sWeah[2 * 264];
    u32 sWebTh[2 * 136];
    float sbea[64];
    float sbeb[16];
  } em;                             // edge part: ~3.5 KB
};

// ---------- kernel A: co-launched {degree count + edge-MLP} || {LN + QKV + seq-norm} ----------
__global__ __launch_bounds__(512) void fusedA(
    const int* __restrict__ ei, const float* __restrict__ edge_attr,
    const float* __restrict__ We0a, const float* __restrict__ be0a,
    const float* __restrict__ We0b, const float* __restrict__ be0b,
    const float* __restrict__ We1a, const float* __restrict__ be1a,
    const float* __restrict__ We1b, const float* __restrict__ be1b,
    int* __restrict__ deg, uint4* __restrict__ mtab,
    const float* __restrict__ x, const float* __restrict__ seq,
    const float* __restrict__ ln_g, const float* __restrict__ ln_b,
    const float* __restrict__ Wq, const float* __restrict__ bq,
    const float* __restrict__ Wk, const float* __restrict__ bk,
    const float* __restrict__ Wv, const float* __restrict__ bv,
    __half* __restrict__ qb, __half* __restrict__ kb,
    u16* __restrict__ vb, __half* __restrict__ snb)
{
  __shared__ SmemA sm;
  const int t = threadIdx.x;

  if (blockIdx.x < NEB) {
    // ================= edge part: degree count + edge-type MLP =================
    u32*   sWeah  = sm.em.sWeah;
    u32*   sWebTh = sm.em.sWebTh;
    float* sbea   = sm.em.sbea;
    float* sbeb   = sm.em.sbeb;

    for (int idx = t; idx < 512; idx += 512) {
      int e2 = idx >> 8, rem = idx & 255, j = rem >> 3, q = rem & 7;
      const float* W = e2 ? We1a : We0a;
      sWeah[e2 * 264 + rem] = pack2f(W[j * 16 + 2 * q], W[j * 16 + 2 * q + 1]);
    }
    if (t < 256) {
      int e2 = t >> 7, rem = t & 127, j = rem >> 2, q = rem & 3;
      const float* W = e2 ? We1b : We0b;
      sWebTh[e2 * 136 + rem] = pack2f(W[(2 * q) * 32 + j], W[(2 * q + 1) * 32 + j]);
    }
    if (t < 64) sbea[t] = (t < 32) ? be0a[t] : be1a[t - 32];
    if (t < 16) sbeb[t] = (t < 8) ? be0b[t] : be1b[t - 8];
    __syncthreads();

    const int e = blockIdx.x * 512 + t;
    if (e < EE) {
      atomic_inc_i32(&deg[ei[EE + e]]);

      __half2 ef2[8]; float a16, a17;
      {
        const float2* p2 = (const float2*)(edge_attr + (size_t)e * 18);
        float2 p[9];
        #pragma unroll
        for (int i = 0; i < 9; i++) p[i] = p2[i];
        #pragma unroll
        for (int i = 0; i < 8; i++) ef2[i] = __floats2half2_rn(p[i].x, p[i].y);
        a16 = p[8].x; a17 = p[8].y;
      }
      const int sel = (a17 > a16) ? 1 : 0;
      const u32* Wah = sWeah + sel * 264;
      const u32* Wbh = sWebTh + sel * 136;
      const float* ba = sbea + sel * 32;
      const float* bb = sbeb + sel * 8;

      __half2 m2[4];
      #pragma unroll
      for (int q = 0; q < 4; q++) m2[q] = __floats2half2_rn(bb[2 * q], bb[2 * q + 1]);
      for (int j = 0; j < 32; j++) {
        __half2 a = __floats2half2_rn(0.f, 0.f);
        #pragma unroll
        for (int q = 0; q < 8; q++) a = __hfma2(as_h2(Wah[j * 8 + q]), ef2[q], a);
        float hs = h2_lo(a) + h2_hi(a) + ba[j];
        hs = fmaxf(hs, 0.f);
        __half2 hs2 = __float2half2_rn(hs);
        #pragma unroll
        for (int q = 0; q < 4; q++) m2[q] = __hfma2(as_h2(Wbh[j * 4 + q]), hs2, m2[q]);
      }
      uint4 st;
      st.x = __builtin_bit_cast(u32, m2[0]);
      st.y = __builtin_bit_cast(u32, m2[1]);
      st.z = __builtin_bit_cast(u32, m2[2]);
      st.w = __builtin_bit_cast(u32, m2[3]);
      mtab[e] = st;
    }
    return;
  }

  // ================= node part: LN + seq-normalize + MFMA QKV =================
  const int nbase = (blockIdx.x - NEB) * 64;
  {
    const int row = t >> 3, sub = t & 7;
    const int n = nbase + row;
    if (n < NN) {
      const float* xp = x + (size_t)n * 128 + sub * 16;
      float vals[16];
      float s = 0.f, ss = 0.f;
      #pragma unroll
      for (int j = 0; j < 16; j += 4) {
        float4 v4 = *(const float4*)(xp + j);
        vals[j] = v4.x; vals[j+1] = v4.y; vals[j+2] = v4.z; vals[j+3] = v4.w;
        s += v4.x + v4.y + v4.z + v4.w;
        ss += v4.x*v4.x + v4.y*v4.y + v4.z*v4.z + v4.w*v4.w;
      }
      #pragma unroll
      for (int o = 1; o < 8; o <<= 1) { s += __shfl_xor(s, o); ss += __shfl_xor(ss, o); }
      float mu = s * (1.f / 128.f);
      float var = ss * (1.f / 128.f) - mu * mu;
      float rs = rsqrtf(var + 1e-5f);
      #pragma unroll
      for (int j = 0; j < 16; j += 2) {
        int c = sub * 16 + j;
        float v0 = (vals[j]   - mu) * rs * ln_g[c]   + ln_b[c];
        float v1 = (vals[j+1] - mu) * rs * ln_g[c+1] + ln_b[c+1];
        *(u32*)&sm.h16[row][c] = pack2f(v0, v1);
      }
      const float* sp = seq + (size_t)n * 64 + sub * 8;
      float4 a = *(const float4*)(sp);
      float4 b4 = *(const float4*)(sp + 4);
      float q2 = a.x*a.x + a.y*a.y + a.z*a.z + a.w*a.w
               + b4.x*b4.x + b4.y*b4.y + b4.z*b4.z + b4.w*b4.w;
      #pragma unroll
      for (int o = 1; o < 8; o <<= 1) q2 += __shfl_xor(q2, o);
      float inv = 1.0f / fmaxf(sqrtf(q2), 1e-12f);
      __half* op = snb + (size_t)n * 64 + sub * 8;
      op[0]=__float2half(a.x*inv);  op[1]=__float2half(a.y*inv);
      op[2]=__float2half(a.z*inv);  op[3]=__float2half(a.w*inv);
      op[4]=__float2half(b4.x*inv); op[5]=__float2half(b4.y*inv);
      op[6]=__float2half(b4.z*inv); op[7]=__float2half(b4.w*inv);
    }
  }

  const int lane = t & 63, wid = t >> 6;
  const int lr = lane & 15;
  const int lk = lane >> 4;
  const int tile0 = wid * 3;

  FragU Bf[3][4];
  float bias[3];
  #pragma unroll
  for (int ti = 0; ti < 3; ti++) {
    int tile = tile0 + ti;
    int mat = tile >> 3;
    int colm = (tile & 7) * 16 + lr;
    const float* W = (mat == 0) ? Wq : (mat == 1) ? Wk : Wv;
    const float* B = (mat == 0) ? bq : (mat == 1) ? bk : bv;
    bias[ti] = B[colm];
    const float* wrow = W + (size_t)colm * 128;
    #pragma unroll
    for (int ks = 0; ks < 4; ks++) {
      const float* wp = wrow + ks * 32 + lk * 8;
      float4 wa = *(const float4*)(wp);
      float4 wb = *(const float4*)(wp + 4);
      Bf[ti][ks].u.x = pack2f(wa.x, wa.y);
      Bf[ti][ks].u.y = pack2f(wa.z, wa.w);
      Bf[ti][ks].u.z = pack2f(wb.x, wb.y);
      Bf[ti][ks].u.w = pack2f(wb.z, wb.w);
    }
  }
  __syncthreads();

  #pragma unroll
  for (int mt = 0; mt < 4; mt++) {
    FragU A[4];
    #pragma unroll
    for (int ks = 0; ks < 4; ks++)
      A[ks].u = *(const uint4*)&sm.h16[mt * 16 + lr][ks * 32 + lk * 8];
    #pragma unroll
    for (int ti = 0; ti < 3; ti++) {
      f32x4 acc = { bias[ti], bias[ti], bias[ti], bias[ti] };
      #pragma unroll
      for (int ks = 0; ks < 4; ks++)
        acc = __builtin_amdgcn_mfma_f32_16x16x32_f16(A[ks].v, Bf[ti][ks].v, acc, 0, 0, 0);
      int tile = tile0 + ti;
      int mat = tile >> 3;
      int colm = (tile & 7) * 16 + lr;
      __half* Oh = (mat == 0) ? qb : kb;
      #pragma unroll
      for (int r = 0; r < 4; r++) {
        int node = nbase + mt * 16 + lk * 4 + r;
        if (node < NN) {
          float val = acc[r];
          if (mat == 2) vb[(size_t)node * 128 + colm] = f2bf(val);
          else          Oh[(size_t)node * 128 + colm] = __float2half(val);
        }
      }
    }
  }
}

// ---------- CSR build ----------
__global__ __launch_bounds__(256) void chunksum_k(const int* __restrict__ deg, int* __restrict__ csum)
{
  const int c = blockIdx.x * 4 + (threadIdx.x >> 6);
  const int lane = threadIdx.x & 63;
  const int idx = c * 64 + lane;
  int v = (idx < NN) ? deg[idx] : 0;
  #pragma unroll
  for (int o = 1; o < 64; o <<= 1) v += __shfl_xor(v, o);
  if (lane == 0) csum[c] = v;
}

__global__ __launch_bounds__(64) void chunkscan_k(const int* __restrict__ csum, int* __restrict__ cbase)
{
  const int lane = threadIdx.x;
  const int CH = 13;
  const int base = lane * CH;
  int s = 0;
  #pragma unroll
  for (int j = 0; j < CH; j++) {
    int c = base + j;
    s += (c < NCHUNK) ? csum[c] : 0;
  }
  int inc = s;
  #pragma unroll
  for (int off = 1; off < 64; off <<= 1) {
    int v = __shfl_up(inc, off);
    if (lane >= off) inc += v;
  }
  int run = inc - s;
  #pragma unroll
  for (int j = 0; j < CH; j++) {
    int c = base + j;
    if (c < NCHUNK) {
      cbase[c] = run;
      run += csum[c];
    }
  }
}

__global__ __launch_bounds__(256) void writeoffs_k(
    const int* __restrict__ deg, const int* __restrict__ cbase,
    int* __restrict__ offs, int* __restrict__ cursor)
{
  const int c = blockIdx.x * 4 + (threadIdx.x >> 6);
  const int lane = threadIdx.x & 63;
  const int idx = c * 64 + lane;
  int d = (idx < NN) ? deg[idx] : 0;
  int inc = d;
  #pragma unroll
  for (int off = 1; off < 64; off <<= 1) {
    int v = __shfl_up(inc, off);
    if (lane >= off) inc += v;
  }
  int off_ = cbase[c] + inc - d;
  if (idx < NN) {
    offs[idx] = off_;
    cursor[idx] = off_;
  }
}

// CSR-ordered arrays: psrc (src node), pe (edge id), dstOf (dst node)
__global__ __launch_bounds__(256) void scatter_pairs_k(
    const int* __restrict__ ei, int* __restrict__ cursor,
    int* __restrict__ psrc, int* __restrict__ pe, int* __restrict__ dstOf)
{
  int e = blockIdx.x * 256 + threadIdx.x;
  int src = ei[e];
  int dst = ei[EE + e];
  int pos = atomic_inc_i32(&cursor[dst]);
  psrc[pos]  = src;
  pe[pos]    = e;
  dstOf[pos] = dst;
}

// ---------- kernel 2: FUSED, CSR-SLOT-ORDERED seq-MLP (MFMA) + mtab + QK + exp ----------
__global__ __launch_bounds__(256, 5) void edge_fused(
    const uint4* __restrict__ mtab,
    const __half* __restrict__ qb, const __half* __restrict__ kb,
    const __half* __restrict__ snb,
    const int* __restrict__ psrc, const int* __restrict__ pe,
    const int* __restrict__ dstOf,
    const float* __restrict__ Ws1, const float* __restrict__ bs1,
    const float* __restrict__ Ws2, const float* __restrict__ bs2,
    uint4* __restrict__ exw)
{
  __shared__ __align__(16) u16 h1lds[4][16][72];    // half-width h1 (+8 pad) / sb redistribution
  __shared__ __align__(16) uint4 sWs1F[1024];       // Ws1 frags (16 KB)
  __shared__ __align__(16) uint4 sWs2F[128];        // Ws2 frags (2 KB)

  const int t = threadIdx.x;
  const int lane = t & 63, wid = t >> 6;
  const int lr = lane & 15;
  const int lk = lane >> 4;
  const int ibase = blockIdx.x * 256 + wid * 64;    // CSR slot base for this wave

  // --- stage seq-MLP weight FRAGMENTS into LDS ---
  for (int fid = t; fid < 1024; fid += 256) {
    int lf = fid & 63, tk = (fid >> 6) & 1, jt = fid >> 7;
    int lrf = lf & 15, lkf = lf >> 4;
    const float* wp = Ws1 + (size_t)(jt * 16 + lrf) * 64 + tk * 32 + lkf * 8;
    float4 wa = *(const float4*)(wp);
    float4 wb = *(const float4*)(wp + 4);
    uint4 fr;
    fr.x = pack2f(wa.x, wa.y); fr.y = pack2f(wa.z, wa.w);
    fr.z = pack2f(wb.x, wb.y); fr.w = pack2f(wb.z, wb.w);
    sWs1F[fid] = fr;
  }
  if (t < 128) {
    int lrf = t & 7, lkf = (t >> 3) & 3, tk = t >> 5;
    const float* wp = Ws2 + (size_t)lrf * 128 + tk * 32 + lkf * 8;
    float4 wa = *(const float4*)(wp);
    float4 wb = *(const float4*)(wp + 4);
    uint4 fr;
    fr.x = pack2f(wa.x, wa.y); fr.y = pack2f(wa.z, wa.w);
    fr.z = pack2f(wb.x, wb.y); fr.w = pack2f(wb.z, wb.w);
    sWs2F[t] = fr;
  }

  float b1v[8];
  #pragma unroll
  for (int jt = 0; jt < 8; jt++) b1v[jt] = bs1[jt * 16 + lr];
  const float b2v = (lr < 8) ? bs2[lr] : 0.f;

  const int srcR = psrc[ibase + lane];     // coalesced
  const int dstR = dstOf[ibase + lane];    // coalesced, ~segment-constant
  const int eR   = pe[ibase + lane];       // coalesced read, random values
  const char* snbB = (const char*)snb;

  __syncthreads();

  // --- phase A: seq-MLP (MFMA), 4 groups of 16 slots; split GEMM2 ---
  float sbreg[16];
  #pragma unroll
  for (int g = 0; g < 4; g++) {
    const int d_e = __shfl(dstR, g * 16 + lr);
    const int s_e = __shfl(srcR, g * 16 + lr);
    FragU A0, A1;
    {
      uint4 ua = *(const uint4*)(snbB + (size_t)d_e * 128 + 0 * 64 + lk * 16);
      uint4 ub = *(const uint4*)(snbB + (size_t)s_e * 128 + 0 * 64 + lk * 16);
      A0.u.x = __builtin_bit_cast(u32, __hsub2(as_h2(ua.x), as_h2(ub.x)));
      A0.u.y = __builtin_bit_cast(u32, __hsub2(as_h2(ua.y), as_h2(ub.y)));
      A0.u.z = __builtin_bit_cast(u32, __hsub2(as_h2(ua.z), as_h2(ub.z)));
      A0.u.w = __builtin_bit_cast(u32, __hsub2(as_h2(ua.w), as_h2(ub.w)));
      uint4 uc = *(const uint4*)(snbB + (size_t)d_e * 128 + 1 * 64 + lk * 16);
      uint4 ud = *(const uint4*)(snbB + (size_t)s_e * 128 + 1 * 64 + lk * 16);
      A1.u.x = __builtin_bit_cast(u32, __hsub2(as_h2(uc.x), as_h2(ud.x)));
      A1.u.y = __builtin_bit_cast(u32, __hsub2(as_h2(uc.y), as_h2(ud.y)));
      A1.u.z = __builtin_bit_cast(u32, __hsub2(as_h2(uc.z), as_h2(ud.z)));
      A1.u.w = __builtin_bit_cast(u32, __hsub2(as_h2(uc.w), as_h2(ud.w)));
    }
    f32x4 acc2 = { b2v, b2v, b2v, b2v };
    #pragma unroll
    for (int jt = 0; jt < 4; jt++) {
      FragU Bf0, Bf1;
      Bf0.u = sWs1F[(jt * 2 + 0) * 64 + lane];
      Bf1.u = sWs1F[(jt * 2 + 1) * 64 + lane];
      f32x4 acc = { b1v[jt], b1v[jt], b1v[jt], b1v[jt] };
      acc = __builtin_amdgcn_mfma_f32_16x16x32_f16(A0.v, Bf0.v, acc, 0, 0, 0);
      acc = __builtin_amdgcn_mfma_f32_16x16x32_f16(A1.v, Bf1.v, acc, 0, 0, 0);
      #pragma unroll
      for (int r = 0; r < 4; r++) {
        float gg = gelu_fast(acc[r]);
        h1lds[wid][lk * 4 + r][jt * 16 + lr] = __builtin_bit_cast(u16, (_Float16)gg);
      }
    }
    #pragma unroll
    for (int tk = 0; tk < 2; tk++) {
      FragU A2, B2f;
      A2.u = *(const uint4*)&h1lds[wid][lr][tk * 32 + lk * 8];
      if (lr < 8) B2f.u = sWs2F[tk * 32 + lk * 8 + lr];
      else        B2f.u = make_uint4(0, 0, 0, 0);
      acc2 = __builtin_amdgcn_mfma_f32_16x16x32_f16(A2.v, B2f.v, acc2, 0, 0, 0);
    }
    #pragma unroll
    for (int jt = 4; jt < 8; jt++) {
      FragU Bf0, Bf1;
      Bf0.u = sWs1F[(jt * 2 + 0) * 64 + lane];
      Bf1.u = sWs1F[(jt * 2 + 1) * 64 + lane];
      f32x4 acc = { b1v[jt], b1v[jt], b1v[jt], b1v[jt] };
      acc = __builtin_amdgcn_mfma_f32_16x16x32_f16(A0.v, Bf0.v, acc, 0, 0, 0);
      acc = __builtin_amdgcn_mfma_f32_16x16x32_f16(A1.v, Bf1.v, acc, 0, 0, 0);
      #pragma unroll
      for (int r = 0; r < 4; r++) {
        float gg = gelu_fast(acc[r]);
        h1lds[wid][lk * 4 + r][(jt - 4) * 16 + lr] = __builtin_bit_cast(u16, (_Float16)gg);
      }
    }
    #pragma unroll
    for (int tk = 2; tk < 4; tk++) {
      FragU A2, B2f;
      A2.u = *(const uint4*)&h1lds[wid][lr][(tk - 2) * 32 + lk * 8];
      if (lr < 8) B2f.u = sWs2F[tk * 32 + lk * 8 + lr];
      else        B2f.u = make_uint4(0, 0, 0, 0);
      acc2 = __builtin_amdgcn_mfma_f32_16x16x32_f16(A2.v, B2f.v, acc2, 0, 0, 0);
    }
    #pragma unroll
    for (int r = 0; r < 4; r++) sbreg[g * 4 + r] = acc2[r];
  }

  // --- sb redistribution through h1lds (wave-private reuse) ---
  u16* sbuf = &h1lds[wid][0][0];
  if (lr < 8) {
    #pragma unroll
    for (int g = 0; g < 4; g++)
      #pragma unroll
      for (int r = 0; r < 4; r++)
        sbuf[(g * 16 + lk * 4 + r) * 8 + lr] =
            __builtin_bit_cast(u16, (_Float16)sbreg[g * 4 + r]);
  }

  // --- phase B: thread-per-slot ---
  const int src = srcR;
  const int dst = dstR;

  float m[8];
  {
    uint4 mm = mtab[eR];        // 16 B scattered, L3-resident table
    u32 wv[4] = {mm.x, mm.y, mm.z, mm.w};
    #pragma unroll
    for (int q = 0; q < 4; q++) {
      m[2*q]   = h2_lo(as_h2(wv[q]));
      m[2*q+1] = h2_hi(as_h2(wv[q]));
    }
  }

  float tv[8];
  {
    uint4 sb4 = ((const uint4*)sbuf)[lane];
    u32 wv[4] = {sb4.x, sb4.y, sb4.z, sb4.w};
    #pragma unroll
    for (int q = 0; q < 4; q++) {
      tv[2*q]   = tanh_fast(h2_lo(as_h2(wv[q])));
      tv[2*q+1] = tanh_fast(h2_hi(as_h2(wv[q])));
    }
  }

  {
    const uint4* qp4 = (const uint4*)(qb + (size_t)dst * 128);
    const uint4* kp4 = (const uint4*)(kb + (size_t)src * 128);
    float ex[8];
    #pragma unroll
    for (int h = 0; h < 8; h++) {
      uint4 qa = qp4[2*h], qc = qp4[2*h+1];
      uint4 ka = kp4[2*h], kc = kp4[2*h+1];
      __half2 d2 = __floats2half2_rn(0.f, 0.f);
      d2 = __hfma2(as_h2(qa.x), as_h2(ka.x), d2);
      d2 = __hfma2(as_h2(qa.y), as_h2(ka.y), d2);
      d2 = __hfma2(as_h2(qa.z), as_h2(ka.z), d2);
      d2 = __hfma2(as_h2(qa.w), as_h2(ka.w), d2);
      d2 = __hfma2(as_h2(qc.x), as_h2(kc.x), d2);
      d2 = __hfma2(as_h2(qc.y), as_h2(kc.y), d2);
      d2 = __hfma2(as_h2(qc.z), as_h2(kc.z), d2);
      d2 = __hfma2(as_h2(qc.w), as_h2(kc.w), d2);
      float dot = h2_lo(d2) + h2_hi(d2);
      float logit = dot * 0.25f + m[h] + 0.1f * tv[h];
      ex[h] = __expf(logit);
    }
    uint4 st;
    st.x = (u32)f2bf(ex[0]) | ((u32)f2bf(ex[1]) << 16);
    st.y = (u32)f2bf(ex[2]) | ((u32)f2bf(ex[3]) << 16);
    st.z = (u32)f2bf(ex[4]) | ((u32)f2bf(ex[5]) << 16);
    st.w = (u32)f2bf(ex[6]) | ((u32)f2bf(ex[7]) << 16);
    exw[ibase + lane] = st;    // coalesced, CSR-ordered
  }
}

// ---------- kernel 3: wave-per-node CSR aggregate (8-deep) + gelu + residual ----------
__global__ __launch_bounds__(256) void aggregate_k(
    const int* __restrict__ offs, const int* __restrict__ deg,
    const int* __restrict__ psrc, const u32* __restrict__ exw,
    const u32* __restrict__ vb32, const float* __restrict__ x,
    float* __restrict__ out)
{
  const int n = (blockIdx.x * 256 + threadIdx.x) >> 6;   // wave per node
  const int lane = threadIdx.x & 63;
  if (n >= NN) return;
  const int s = offs[n];
  const int end = s + deg[n];
  const int word  = lane >> 4;
  const int shift = ((lane >> 3) & 1) << 4;

  float s0 = 0.f, s1 = 0.f, dn = 0.f;
  int i = s;
  for (; i + 8 <= end; i += 8) {
    int  pp[8]; u32 kk[8]; u32 vv[8];
    #pragma unroll
    for (int q = 0; q < 8; q++) pp[q] = psrc[i + q];
    #pragma unroll
    for (int q = 0; q < 8; q++) kk[q] = exw[(size_t)(i + q) * 4 + word];
    #pragma unroll
    for (int q = 0; q < 8; q++) vv[q] = vb32[(size_t)pp[q] * 64 + lane];
    #pragma unroll
    for (int q = 0; q < 8; q++) {
      float ex = __uint_as_float(((kk[q] >> shift) & 0xffffu) << 16);
      s0 = fmaf(bf_lo(vv[q]), ex, s0);
      s1 = fmaf(bf_hi(vv[q]), ex, s1);
      dn += ex;
    }
  }
  for (; i < end; i++) {
    int sp = psrc[i];
    u32 pkv = exw[(size_t)i * 4 + word];
    float ex = __uint_as_float(((pkv >> shift) & 0xffffu) << 16);
    u32 vv = vb32[(size_t)sp * 64 + lane];
    s0 = fmaf(bf_lo(vv), ex, s0);
    s1 = fmaf(bf_hi(vv), ex, s1);
    dn += ex;
  }
  float inv = 1.0f / (dn + 1e-12f);
  float2 xx = *(const float2*)(x + (size_t)n * 128 + lane * 2);
  float2 o;
  o.x = gelu_exact(s0 * inv) + xx.x;
  o.y = gelu_exact(s1 * inv) + xx.y;
  *(float2*)(out + (size_t)n * 128 + lane * 2) = o;
}

extern "C" void kernel_launch(void* const* d_in, const int* in_sizes, int n_in,
                              void* d_out, int out_size, void* d_ws, size_t ws_size,
                              hipStream_t stream)
{
  const float* x    = (const float*)d_in[0];
  const int*   ei   = (const int*)d_in[1];
  const float* ea   = (const float*)d_in[2];
  const float* seq  = (const float*)d_in[3];
  const float* ln_g = (const float*)d_in[4];
  const float* ln_b = (const float*)d_in[5];
  const float* Wq   = (const float*)d_in[6];
  const float* bq   = (const float*)d_in[7];
  const float* Wk   = (const float*)d_in[8];
  const float* bk   = (const float*)d_in[9];
  const float* Wv   = (const float*)d_in[10];
  const float* bv   = (const float*)d_in[11];
  const float* We0a = (const float*)d_in[12];
  const float* be0a = (const float*)d_in[13];
  const float* We0b = (const float*)d_in[14];
  const float* be0b = (const float*)d_in[15];
  const float* We1a = (const float*)d_in[16];
  const float* be1a = (const float*)d_in[17];
  const float* We1b = (const float*)d_in[18];
  const float* be1b = (const float*)d_in[19];
  const float* Ws1  = (const float*)d_in[20];
  const float* bs1  = (const float*)d_in[21];
  const float* Ws2  = (const float*)d_in[22];
  const float* bs2  = (const float*)d_in[23];
  float* out = (float*)d_out;

  // workspace layout (~81 MB)
  char* w = (char*)d_ws;
  __half* qb   = (__half*)w;                       w += (size_t)NN * 128 * 2;
  __half* kb   = (__half*)w;                       w += (size_t)NN * 128 * 2;
  u16*    vb   = (u16*)w;                          w += (size_t)NN * 128 * 2;
  __half* snb  = (__half*)w;                       w += (size_t)NN * 64 * 2;
  uint4*  exw  = (uint4*)w;                        w += (size_t)EE * 16;
  uint4*  mtab = (uint4*)w;                        w += (size_t)EE * 16;
  int*    psrc = (int*)w;                          w += (size_t)EE * 4;
  int*    pe   = (int*)w;                          w += (size_t)EE * 4;
  int*    dstOf= (int*)w;                          w += (size_t)EE * 4;
  int*    deg  = (int*)w;                          w += (size_t)NN * 4;
  int*    offs = (int*)w;                          w += (size_t)NN * 4;
  int*    cursor = (int*)w;                        w += (size_t)NN * 4;
  int*    csum = (int*)w;                          w += (size_t)NCHUNK * 4;
  int*    cbase = (int*)w;                         w += (size_t)NCHUNK * 4;

  (void)hipMemsetAsync(deg, 0, (size_t)NN * 4, stream);

  fusedA<<<NEB + NNB, 512, 0, stream>>>(
      ei, ea, We0a, be0a, We0b, be0b, We1a, be1a, We1b, be1b, deg, mtab,
      x, seq, ln_g, ln_b, Wq, bq, Wk, bk, Wv, bv, qb, kb, vb, snb);

  chunksum_k<<<NCHUNK / 4, 256, 0, stream>>>(deg, csum);
  chunkscan_k<<<1, 64, 0, stream>>>(csum, cbase);
  writeoffs_k<<<NCHUNK / 4, 256, 0, stream>>>(deg, cbase, offs, cursor);
  scatter_pairs_k<<<EE / 256, 256, 0, stream>>>(ei, cursor, psrc, pe, dstOf);

  edge_fused<<<EE / 256, 256, 0, stream>>>(
      mtab, qb, kb, snb, psrc, pe, dstOf,
      Ws1, bs1, Ws2, bs2, exw);

  aggregate_k<<<(NN * 64) / 256, 256, 0, stream>>>(
      offs, deg, psrc, (const u32*)exw, (const u32*)vb, x, out);
}